// Round 17
// baseline (390.833 us; speedup 1.0000x reference)
//
#include <hip/hip_runtime.h>
#include <math.h>

// PruningAgent r16: r15's pre-scaled-G' pure-add agg + r14's 3-phase CSR
// (count w/ rank, scan, atomic-free fill into COMPACT eg). r15's fused
// CAP-bucket build had 13x write amplification (91 MB for 6.8 MB payload).

typedef unsigned short ushort_t;
using short8 = __attribute__((ext_vector_type(8))) short;
using f32x4  = __attribute__((ext_vector_type(4))) float;

constexpr int N_L  = 40000;
constexpr int E_L  = 640000;
constexpr int L_H  = 8;
constexpr int N_H1 = 8192;
constexpr int E_H1 = 131072;
constexpr int N_HT = 65536;    // 8*8192
constexpr int E_HT = 1048576;  // 8*131072
constexpr int E_T  = E_L + E_HT;
constexpr int NLP  = 40064;    // layer rows padded to 128 (313*128)
constexpr int R_T  = 105600;   // NLP + N_HT
constexpr int HBASE = 40064;

// workspace byte offsets
constexpr size_t OFF_SAF  = 0;                            // NLP*512 fp32 G' (rank overlay pre-enc)
constexpr size_t OFF_HB   = (size_t)NLP * 512;            // N_HT*256 bf16 G'
constexpr size_t OFF_ZPAD = OFF_HB + (size_t)N_HT * 256;  // 512 B zeros
constexpr size_t OFF_SBH  = OFF_ZPAD + 512;               // R_T*256
constexpr size_t OFF_SBL  = OFF_SBH + (size_t)R_T * 256;  // NLP*256
constexpr size_t OFF_WTH  = OFF_SBL + (size_t)NLP * 256;  // 229376
constexpr size_t OFF_WTL  = OFF_WTH + 229376;
constexpr size_t OFF_DINV = OFF_WTL + 229376;             // R_T*4
constexpr size_t OFF_HSUM = OFF_DINV + (size_t)R_T * 4;   // 512
constexpr size_t OFF_DEG  = OFF_HSUM + 512;               // R_T*4 indeg
constexpr size_t OFF_RP   = OFF_DEG + (size_t)R_T * 4;    // (R_T+1)*4 rowptr
constexpr size_t OFF_EG   = OFF_RP + (size_t)(R_T + 1) * 4;  // (E_T+16)*4
constexpr size_t OFF_BSUM = OFF_EG + (size_t)(E_T + 16) * 4; // 512

constexpr int ZIDX_L = (int)(OFF_ZPAD / 512);   // float4-row index of zero row
constexpr int ZIDX_H = R_T;                     // head-row index of zero row

static_assert(OFF_ZPAD % 512 == 0, "zpad alignment");

// ---------------- numeric helpers ----------------

__device__ __forceinline__ unsigned short bf16_rne(float f) {
  unsigned u = __float_as_uint(f);
  unsigned r = u + 0x7FFFu + ((u >> 16) & 1u);
  return (unsigned short)(r >> 16);
}
__device__ __forceinline__ float bfhi_f(unsigned short h) {
  return __uint_as_float((unsigned)h << 16);
}
__device__ __forceinline__ void split2(float f, unsigned short& h, unsigned short& l) {
  h = bf16_rne(f);
  l = bf16_rne(f - bfhi_f(h));
}

__device__ __forceinline__ void gload16(const void* g, void* l) {
  __builtin_amdgcn_global_load_lds((__attribute__((address_space(1))) void*)(g),
                                   (__attribute__((address_space(3))) void*)(l),
                                   16, 0, 0);
}

// ---------------- degree / CSR build (3-phase, atomic-free fill) ----------

__global__ __launch_bounds__(256) void count_deg_all(const int* __restrict__ ei,
                                                     const int* __restrict__ hei,
                                                     int* __restrict__ indeg,
                                                     int* __restrict__ rank) {
  int i = blockIdx.x * 256 + threadIdx.x;
  if (i < E_L) {
    rank[i] = atomicAdd(&indeg[ei[E_L + i]], 1);
  } else if (i < E_T) {
    int t = i - E_L;
    int l = t >> 17, e = t & (E_H1 - 1);
    rank[i] = atomicAdd(&indeg[HBASE + l * N_H1 + hei[l * 2 * E_H1 + E_H1 + e]], 1);
  }
}

__global__ __launch_bounds__(256) void dinv_kernel(const int* __restrict__ indeg,
                                                   float* __restrict__ dinv, int n) {
  int i = blockIdx.x * 256 + threadIdx.x;
  if (i < n) dinv[i] = 1.0f / sqrtf((float)(indeg[i] + 1));
}

__global__ __launch_bounds__(1024) void scan_block(const int* __restrict__ in, int n,
                                                   int* __restrict__ out,
                                                   int* __restrict__ bsum) {
  __shared__ int s[1024];
  int t = threadIdx.x;
  int i = blockIdx.x * 1024 + t;
  int v = (i < n) ? in[i] : 0;
  s[t] = v;
  __syncthreads();
  for (int off = 1; off < 1024; off <<= 1) {
    int x = (t >= off) ? s[t - off] : 0;
    __syncthreads();
    s[t] += x;
    __syncthreads();
  }
  if (i < n) out[i] = s[t] - v;
  if (t == 1023) bsum[blockIdx.x] = s[t];
}

__global__ __launch_bounds__(64) void scan_top128(int* __restrict__ bsum, int nb) {
  int lane = threadIdx.x;
  int a = (lane < nb) ? bsum[lane] : 0;
  int b = (lane + 64 < nb) ? bsum[lane + 64] : 0;
  int ia = a;
  for (int off = 1; off < 64; off <<= 1) {
    int x = __shfl_up(ia, off);
    if (lane >= off) ia += x;
  }
  int ta = __shfl(ia, 63);
  int ib = b;
  for (int off = 1; off < 64; off <<= 1) {
    int x = __shfl_up(ib, off);
    if (lane >= off) ib += x;
  }
  int tb = __shfl(ib, 63);
  if (lane < nb) bsum[lane] = ia - a;
  if (lane + 64 < nb) bsum[lane + 64] = ta + ib - b;
  if (lane == 0) bsum[nb] = ta + tb;
}

__global__ __launch_bounds__(256) void scan_fix(int* __restrict__ rowptr,
                                                const int* __restrict__ bsum,
                                                int n, int nb) {
  int i = blockIdx.x * 256 + threadIdx.x;
  if (i < n) {
    rowptr[i] += bsum[i >> 10];
  } else if (i == n) {
    rowptr[n] = bsum[nb];
  }
}

__global__ __launch_bounds__(256) void fill_csr_all(const int* __restrict__ ei,
                                                    const int* __restrict__ hei,
                                                    const int* __restrict__ rowptr,
                                                    const int* __restrict__ rank,
                                                    unsigned* __restrict__ eg) {
  int i = blockIdx.x * 256 + threadIdx.x;
  if (i < E_L) {
    int dst = ei[E_L + i];
    int src = ei[i];
    eg[rowptr[dst] + rank[i]] = (unsigned)src;
  } else if (i < E_T) {
    int t = i - E_L;
    int l = t >> 17, e = t & (E_H1 - 1);
    int b2 = l * 2 * E_H1;
    int dst = HBASE + l * N_H1 + hei[b2 + E_H1 + e];
    int src = HBASE + l * N_H1 + hei[b2 + e];
    eg[rowptr[dst] + rank[i]] = (unsigned)src;
  }
}

// ---------------- weight pre-split (transposed) ----------------

__global__ __launch_bounds__(256) void conv_weights(
    const float* __restrict__ w0, const float* __restrict__ w1,
    const float* __restrict__ w2, const float* __restrict__ w3,
    const float* __restrict__ w4, const float* __restrict__ w5,
    unsigned short* __restrict__ th, unsigned short* __restrict__ tl) {
  int t = blockIdx.x * 256 + threadIdx.x;
  const float* src; int K, dstoff, idx;
  if (t < 32768) { src = w0; K = 256; dstoff = 0; idx = t; }
  else {
    int s = (t - 32768) >> 14;
    idx = (t - 32768) & 16383;
    K = 128;
    dstoff = 32768 + s * 16384;
    src = s == 0 ? w1 : s == 1 ? w2 : s == 2 ? w3 : s == 3 ? w4 : w5;
  }
  int k = idx >> 7, c = idx & 127;
  unsigned short h_, l_;
  split2(src[idx], h_, l_);
  th[dstoff + c * K + k] = h_;
  tl[dstoff + c * K + k] = l_;
}

// ---------------- shared mm helpers (KC=64 chunk), SPLIT-templated -------

template <bool SPLIT>
__device__ __forceinline__ void stage_w_t(const unsigned short* Wth,
                                          const unsigned short* Wtl, int K, int kc,
                                          char* Ws_h, char* Ws_l,
                                          int wv, int rsub, int xr) {
#pragma unroll
  for (int j = 0; j < 4; ++j) {
    int q = wv * 4 + j;
    int c = q * 8 + rsub;
    size_t gb = ((size_t)c * K + kc) * 2 + (size_t)xr * 16;
    gload16((const char*)Wth + gb, Ws_h + q * 1024);
    if constexpr (SPLIT) gload16((const char*)Wtl + gb, Ws_l + q * 1024);
  }
}

template <bool SPLIT>
__device__ __forceinline__ void mfma_chunk_t(const char* As_h, const char* As_l,
                                             const char* Ws_h, const char* Ws_l,
                                             int wv, int g, int li,
                                             f32x4 acc[2][8]) {
  short8 fa_h[2][2], fa_l[2][2];
#pragma unroll
  for (int m = 0; m < 2; ++m)
#pragma unroll
    for (int ks = 0; ks < 2; ++ks) {
      int row = wv * 32 + m * 16 + li;
      int off = row * 128 + ks * 64 + g * 16;
      off ^= (row & 7) << 4;
      fa_h[m][ks] = *(const short8*)(As_h + off);
      if constexpr (SPLIT) fa_l[m][ks] = *(const short8*)(As_l + off);
    }
#pragma unroll
  for (int nh = 0; nh < 2; ++nh) {
    short8 fb_h[4][2], fb_l[4][2];
#pragma unroll
    for (int n = 0; n < 4; ++n)
#pragma unroll
      for (int ks = 0; ks < 2; ++ks) {
        int c = nh * 64 + n * 16 + li;
        int off = c * 128 + ks * 64 + g * 16;
        off ^= (c & 7) << 4;
        fb_h[n][ks] = *(const short8*)(Ws_h + off);
        if constexpr (SPLIT) fb_l[n][ks] = *(const short8*)(Ws_l + off);
      }
#pragma unroll
    for (int m = 0; m < 2; ++m)
#pragma unroll
      for (int n = 0; n < 4; ++n)
#pragma unroll
        for (int ks = 0; ks < 2; ++ks) {
          f32x4 a_ = acc[m][nh * 4 + n];
          a_ = __builtin_amdgcn_mfma_f32_16x16x32_bf16(fa_h[m][ks], fb_h[n][ks], a_, 0, 0, 0);
          if constexpr (SPLIT) {
            a_ = __builtin_amdgcn_mfma_f32_16x16x32_bf16(fa_h[m][ks], fb_l[n][ks], a_, 0, 0, 0);
            a_ = __builtin_amdgcn_mfma_f32_16x16x32_bf16(fa_l[m][ks], fb_h[n][ks], a_, 0, 0, 0);
          }
          acc[m][nh * 4 + n] = a_;
        }
  }
}

template <bool SPLIT>
__device__ __forceinline__ void write_h_slice_t(const f32x4 acc[2][8],
                                                const float* bj, int kc,
                                                char* As_h, char* As_l,
                                                int wv, int g, int li) {
#pragma unroll
  for (int m = 0; m < 2; ++m)
#pragma unroll
    for (int jj = 0; jj < 4; ++jj) {
      int j = (kc >> 4) + jj;
#pragma unroll
      for (int r = 0; r < 4; ++r) {
        float o = fmaxf(acc[m][j][r] + bj[j], 0.f);
        int row = wv * 32 + m * 16 + g * 4 + r;
        int cl = jj * 16 + li;
        int byte = row * 128 + ((((cl >> 3) ^ (row & 7)) << 4) | ((cl & 7) * 2));
        if constexpr (SPLIT) {
          unsigned short h_, l_;
          split2(o, h_, l_);
          *(unsigned short*)(As_h + byte) = h_;
          *(unsigned short*)(As_l + byte) = l_;
        } else {
          *(unsigned short*)(As_h + byte) = bf16_rne(o);
        }
      }
    }
}

// G' epilogue: layer rows -> fp32 dinv*h; head rows -> bf16 dinv*h
__device__ __forceinline__ void write_g_out(const f32x4 acc[2][8],
                                            const float* __restrict__ dinvg,
                                            float* __restrict__ G,
                                            unsigned short* __restrict__ Hb,
                                            int row0, int wv, int g, int li) {
  if (row0 < NLP) {
#pragma unroll
    for (int m = 0; m < 2; ++m)
#pragma unroll
      for (int r = 0; r < 4; ++r) {
        int rowg = row0 + wv * 32 + m * 16 + g * 4 + r;
        float dvr = dinvg[rowg];
#pragma unroll
        for (int j = 0; j < 8; ++j)
          G[(size_t)rowg * 128 + j * 16 + li] = acc[m][j][r] * dvr;
      }
  } else {
#pragma unroll
    for (int m = 0; m < 2; ++m)
#pragma unroll
      for (int r = 0; r < 4; ++r) {
        int rowg = row0 + wv * 32 + m * 16 + g * 4 + r;
        float dvr = dinvg[rowg];
        int rl = rowg - HBASE;
#pragma unroll
        for (int j = 0; j < 8; ++j)
          Hb[(size_t)rl * 128 + j * 16 + li] = bf16_rne(acc[m][j][r] * dvr);
      }
  }
}

// ---------------- fused encoder + g1 matmul ----------------

template <bool SPLIT>
__device__ __forceinline__ void enc_body(
    const float* __restrict__ xs, int lclamp,
    const unsigned short* __restrict__ W1h, const unsigned short* __restrict__ W1l,
    const unsigned short* __restrict__ W2h, const unsigned short* __restrict__ W2l,
    const unsigned short* __restrict__ Wgh, const unsigned short* __restrict__ Wgl,
    const float* __restrict__ b1, const float* __restrict__ b2,
    const float* __restrict__ dinvg,
    float* __restrict__ G, unsigned short* __restrict__ Hb,
    char* As_h, char* As_l, char* Ws_h, char* Ws_l,
    int tid, int wv, int g, int li, int row0, int lrow0, int rsub, int xr) {
  float bj1[8], bj2[8];
#pragma unroll
  for (int j = 0; j < 8; ++j) {
    bj1[j] = b1[j * 16 + li];
    bj2[j] = b2[j * 16 + li];
  }

  f32x4 acc1[2][8];
#pragma unroll
  for (int m = 0; m < 2; ++m)
#pragma unroll
    for (int j = 0; j < 8; ++j) acc1[m][j] = f32x4{0.f, 0.f, 0.f, 0.f};

#pragma unroll
  for (int kc = 0; kc < 256; kc += 64) {
    __syncthreads();
    stage_w_t<SPLIT>(W1h, W1l, 256, kc, Ws_h, Ws_l, wv, rsub, xr);
    {
      int r = tid >> 1, hf = tid & 1;
      int lrow = min(lrow0 + r, lclamp);
      const float* src = xs + (size_t)lrow * 256 + kc + hf * 32;
#pragma unroll
      for (int i = 0; i < 4; ++i) {
        float4 a = ((const float4*)src)[2 * i];
        float4 b = ((const float4*)src)[2 * i + 1];
        float f[8] = {a.x, a.y, a.z, a.w, b.x, b.y, b.z, b.w};
        short8 vh, vl;
#pragma unroll
        for (int e = 0; e < 8; ++e) {
          if constexpr (SPLIT) {
            unsigned short h_, l_;
            split2(f[e], h_, l_);
            vh[e] = (short)h_;
            vl[e] = (short)l_;
          } else {
            vh[e] = (short)bf16_rne(f[e]);
          }
        }
        int xu = hf * 4 + i;
        int u = r * 8 + (xu ^ (r & 7));
        *(short8*)(As_h + u * 16) = vh;
        if constexpr (SPLIT) *(short8*)(As_l + u * 16) = vl;
      }
    }
    __syncthreads();
    mfma_chunk_t<SPLIT>(As_h, As_l, Ws_h, Ws_l, wv, g, li, acc1);
  }

  f32x4 acc2[2][8];
#pragma unroll
  for (int m = 0; m < 2; ++m)
#pragma unroll
    for (int j = 0; j < 8; ++j) acc2[m][j] = f32x4{0.f, 0.f, 0.f, 0.f};

#pragma unroll
  for (int kc = 0; kc < 128; kc += 64) {
    __syncthreads();
    stage_w_t<SPLIT>(W2h, W2l, 128, kc, Ws_h, Ws_l, wv, rsub, xr);
    write_h_slice_t<SPLIT>(acc1, bj1, kc, As_h, As_l, wv, g, li);
    __syncthreads();
    mfma_chunk_t<SPLIT>(As_h, As_l, Ws_h, Ws_l, wv, g, li, acc2);
  }

  f32x4 acc3[2][8];
#pragma unroll
  for (int m = 0; m < 2; ++m)
#pragma unroll
    for (int j = 0; j < 8; ++j) acc3[m][j] = f32x4{0.f, 0.f, 0.f, 0.f};

#pragma unroll
  for (int kc = 0; kc < 128; kc += 64) {
    __syncthreads();
    stage_w_t<SPLIT>(Wgh, Wgl, 128, kc, Ws_h, Ws_l, wv, rsub, xr);
    write_h_slice_t<SPLIT>(acc2, bj2, kc, As_h, As_l, wv, g, li);
    __syncthreads();
    mfma_chunk_t<SPLIT>(As_h, As_l, Ws_h, Ws_l, wv, g, li, acc3);
  }

  write_g_out(acc3, dinvg, G, Hb, row0, wv, g, li);
}

__global__ __launch_bounds__(256, 2) void enc_fused(
    const float* __restrict__ x, const float* __restrict__ head_x,
    const unsigned short* __restrict__ W1h, const unsigned short* __restrict__ W1l,
    const unsigned short* __restrict__ W2h, const unsigned short* __restrict__ W2l,
    const unsigned short* __restrict__ Wgh, const unsigned short* __restrict__ Wgl,
    const float* __restrict__ b1, const float* __restrict__ b2,
    const float* __restrict__ dinvg,
    float* __restrict__ G, unsigned short* __restrict__ Hb) {
  __shared__ __align__(16) char lds[65536];
  char* As_h = lds;
  char* As_l = lds + 16384;
  char* Ws_h = lds + 32768;
  char* Ws_l = lds + 49152;

  const int tid = threadIdx.x;
  const int lane = tid & 63;
  const int wv = tid >> 6;
  const int g = lane >> 4;
  const int li = lane & 15;
  const int row0 = blockIdx.x * 128;
  const int rsub = lane >> 3;
  const int xr = (lane & 7) ^ ((lane >> 3) & 7);

  if (row0 < NLP) {
    enc_body<true>(x, N_L - 1, W1h, W1l, W2h, W2l, Wgh, Wgl, b1, b2, dinvg, G, Hb,
                   As_h, As_l, Ws_h, Ws_l, tid, wv, g, li, row0, row0, rsub, xr);
  } else {
    enc_body<false>(head_x, N_HT - 1, W1h, nullptr, W2h, nullptr, Wgh, nullptr,
                    b1, b2, dinvg, G, Hb,
                    As_h, As_l, Ws_h, Ws_l, tid, wv, g, li, row0, row0 - NLP,
                    rsub, xr);
  }
}

// ---------------- MFMA matmul (g2: split/single in, scaled hybrid out) -----

template <bool SPLIT>
__device__ __forceinline__ void mm_g_body(
    const unsigned short* __restrict__ Ah, const unsigned short* __restrict__ Al,
    const unsigned short* __restrict__ Wth, const unsigned short* __restrict__ Wtl,
    char* As_h, char* As_l, char* Ws_h, char* Ws_l,
    int wv, int g, int li, int row0, int rsub, int xr, f32x4 acc[2][8]) {
  constexpr int K = 128;
#pragma unroll
  for (int kc = 0; kc < K; kc += 64) {
    __syncthreads();
    stage_w_t<SPLIT>(Wth, Wtl, K, kc, Ws_h, Ws_l, wv, rsub, xr);
#pragma unroll
    for (int j = 0; j < 4; ++j) {
      int q = wv * 4 + j;
      int r = q * 8 + rsub;
      size_t gb = ((size_t)(row0 + r) * K + kc) * 2 + (size_t)xr * 16;
      gload16((const char*)Ah + gb, As_h + q * 1024);
      if constexpr (SPLIT) gload16((const char*)Al + gb, As_l + q * 1024);
    }
    __syncthreads();
    mfma_chunk_t<SPLIT>(As_h, As_l, Ws_h, Ws_l, wv, g, li, acc);
  }
}

__global__ __launch_bounds__(256) void mm_g(
    const unsigned short* __restrict__ Ah, const unsigned short* __restrict__ Al,
    const unsigned short* __restrict__ Wth, const unsigned short* __restrict__ Wtl,
    const float* __restrict__ dinvg,
    float* __restrict__ Cf, unsigned short* __restrict__ Hb) {
  __shared__ __align__(16) char lds[65536];
  char* As_h = lds;
  char* As_l = lds + 16384;
  char* Ws_h = lds + 32768;
  char* Ws_l = lds + 49152;

  const int tid = threadIdx.x;
  const int lane = tid & 63;
  const int wv = tid >> 6;
  const int g = lane >> 4;
  const int li = lane & 15;
  const int row0 = blockIdx.x * 128;
  const int rsub = lane >> 3;
  const int xr = (lane & 7) ^ ((lane >> 3) & 7);

  f32x4 acc[2][8];
#pragma unroll
  for (int m = 0; m < 2; ++m)
#pragma unroll
    for (int j = 0; j < 8; ++j) acc[m][j] = f32x4{0.f, 0.f, 0.f, 0.f};

  if (row0 < NLP)
    mm_g_body<true>(Ah, Al, Wth, Wtl, As_h, As_l, Ws_h, Ws_l,
                    wv, g, li, row0, rsub, xr, acc);
  else
    mm_g_body<false>(Ah, nullptr, Wth, nullptr, As_h, As_l, Ws_h, Ws_l,
                     wv, g, li, row0, rsub, xr, acc);

  write_g_out(acc, dinvg, Cf, Hb, row0, wv, g, li);
}

// ---------------- fused policy matmul (lp rows<NLP, hp rows>=NLP) --------

__global__ __launch_bounds__(256) void mm_policy(
    const unsigned short* __restrict__ Ah, const unsigned short* __restrict__ Al,
    const unsigned short* __restrict__ Wth_l, const unsigned short* __restrict__ Wtl_l,
    const unsigned short* __restrict__ Wth_h,
    const float* __restrict__ b1l, const float* __restrict__ b1h,
    const float* __restrict__ w2l, const float* __restrict__ w2h,
    const float* __restrict__ b2l, const float* __restrict__ b2h,
    float* __restrict__ out_l, float* __restrict__ out_h) {
  __shared__ __align__(16) char lds[65536];
  char* As_h = lds;
  char* As_l = lds + 16384;
  char* Ws_h = lds + 32768;
  char* Ws_l = lds + 49152;

  const int tid = threadIdx.x;
  const int lane = tid & 63;
  const int wv = tid >> 6;
  const int g = lane >> 4;
  const int li = lane & 15;
  const int row0 = blockIdx.x * 128;
  const bool isl = row0 < NLP;
  const int rsub = lane >> 3;
  const int xr = (lane & 7) ^ ((lane >> 3) & 7);

  const float* bias = isl ? b1l : b1h;
  const float* pw2  = isl ? w2l : w2h;
  const float* pb2  = isl ? b2l : b2h;

  f32x4 acc[2][8];
#pragma unroll
  for (int m = 0; m < 2; ++m)
#pragma unroll
    for (int j = 0; j < 8; ++j) acc[m][j] = f32x4{0.f, 0.f, 0.f, 0.f};

  if (isl)
    mm_g_body<true>(Ah, Al, Wth_l, Wtl_l, As_h, As_l, Ws_h, Ws_l,
                    wv, g, li, row0, rsub, xr, acc);
  else
    mm_g_body<false>(Ah, nullptr, Wth_h, nullptr, As_h, As_l, Ws_h, Ws_l,
                     wv, g, li, row0, rsub, xr, acc);

  float w2c[8], bj[8];
#pragma unroll
  for (int j = 0; j < 8; ++j) {
    w2c[j] = pw2[j * 16 + li];
    bj[j]  = bias[j * 16 + li];
  }
#pragma unroll
  for (int m = 0; m < 2; ++m)
#pragma unroll
    for (int r = 0; r < 4; ++r) {
      float p = 0.f;
#pragma unroll
      for (int j = 0; j < 8; ++j) {
        float o = fmaxf(acc[m][j][r] + bj[j], 0.f);
        p = fmaf(o, w2c[j], p);
      }
      p += __shfl_xor(p, 1);
      p += __shfl_xor(p, 2);
      p += __shfl_xor(p, 4);
      p += __shfl_xor(p, 8);
      if (li == 0) {
        int rowg = row0 + wv * 32 + m * 16 + g * 4 + r;
        if (isl) {
          if (rowg < N_L) out_l[rowg] = 1.0f / (1.0f + expf(-(p + pb2[0])));
        } else {
          out_h[rowg - HBASE] = 1.0f / (1.0f + expf(-(p + pb2[0])));
        }
      }
    }
}

// ---------------- GCN aggregation (pure-add gather, rowptr CSR) ------------
// out[v] = relu( dinv[v]*(G'[v] + sum_u G'[u]) + b ), G' = dinv*h pre-scaled.

__global__ __launch_bounds__(256) void agg_packed(const float* __restrict__ Hin,
                                                  const unsigned short* __restrict__ Hb,
                                                  const float* __restrict__ dinvg,
                                                  const int* __restrict__ rowptr,
                                                  const unsigned* __restrict__ eg,
                                                  const float* __restrict__ bias,
                                                  unsigned short* __restrict__ Oh,
                                                  unsigned short* __restrict__ Ol) {
  int b = blockIdx.x;                 // 13200 blocks: 5008 layer + 8192 head
  {
    int x = b & 7, j = b >> 3;        // j in [0,1650)
    b = (j < 626) ? (x * 626 + j) : (5008 + x * 1024 + (j - 626));
  }
  const int lane = threadIdx.x & 63;
  const int wv = threadIdx.x >> 6;
  const int half = lane >> 5;
  const int hl = lane & 31;
  const int v = b * 8 + wv * 2 + half;

  const float4* H4 = (const float4*)Hin;
  const ushort4* Hb4 = (const ushort4*)Hb;

  float dv = dinvg[v];
  int e0 = rowptr[v], e1 = rowptr[v + 1];
  int deg = e1 - e0;

  float4 acc;
  if (v < NLP) {
    acc = H4[(size_t)v * 32 + hl];             // G'[v]
  } else {
    ushort4 t = Hb4[(size_t)(v - HBASE) * 32 + hl];
    acc.x = bfhi_f(t.x);
    acc.y = bfhi_f(t.y);
    acc.z = bfhi_f(t.z);
    acc.w = bfhi_f(t.w);
  }

  int nb = (deg + 15) >> 4;
  int nbo = __shfl_xor(nb, 32);
  int nbmax = max(nb, nbo);

  if (v < NLP) {
    for (int t = 0; t < nbmax; ++t) {
      int e = t * 16;
      unsigned pr = 0;
      if (hl < 16 && e + hl < deg) pr = eg[e0 + e + hl];
      float4 xs[16];
#pragma unroll
      for (int i = 0; i < 16; ++i) {
        unsigned pe = (unsigned)__shfl((int)pr, (half << 5) | i);
        int u = (e + i < deg) ? (int)pe : ZIDX_L;
        xs[i] = H4[(size_t)u * 32 + hl];
      }
#pragma unroll
      for (int i = 0; i < 16; ++i) {
        acc.x += xs[i].x;
        acc.y += xs[i].y;
        acc.z += xs[i].z;
        acc.w += xs[i].w;
      }
    }
  } else {
    for (int t = 0; t < nbmax; ++t) {
      int e = t * 16;
      unsigned pr = 0;
      if (hl < 16 && e + hl < deg) pr = eg[e0 + e + hl];
      ushort4 xs[16];
#pragma unroll
      for (int i = 0; i < 16; ++i) {
        unsigned pe = (unsigned)__shfl((int)pr, (half << 5) | i);
        int u = (e + i < deg) ? (int)pe : ZIDX_H;
        xs[i] = Hb4[(size_t)(u - HBASE) * 32 + hl];
      }
#pragma unroll
      for (int i = 0; i < 16; ++i) {
        acc.x += bfhi_f(xs[i].x);
        acc.y += bfhi_f(xs[i].y);
        acc.z += bfhi_f(xs[i].z);
        acc.w += bfhi_f(xs[i].w);
      }
    }
  }

  float4 bb = ((const float4*)bias)[hl];
  acc.x = fmaxf(fmaf(dv, acc.x, bb.x), 0.f);
  acc.y = fmaxf(fmaf(dv, acc.y, bb.y), 0.f);
  acc.z = fmaxf(fmaf(dv, acc.z, bb.z), 0.f);
  acc.w = fmaxf(fmaf(dv, acc.w, bb.w), 0.f);

  if (v < NLP) {
    ushort4 th, tl;
    split2(acc.x, th.x, tl.x);
    split2(acc.y, th.y, tl.y);
    split2(acc.z, th.z, tl.z);
    split2(acc.w, th.w, tl.w);
    ((ushort4*)Oh)[(size_t)v * 32 + hl] = th;
    ((ushort4*)Ol)[(size_t)v * 32 + hl] = tl;
  } else {
    ushort4 th;
    th.x = bf16_rne(acc.x);
    th.y = bf16_rne(acc.y);
    th.z = bf16_rne(acc.z);
    th.w = bf16_rne(acc.w);
    ((ushort4*)Oh)[(size_t)v * 32 + hl] = th;
  }
}

// ---------------- value head ----------------

__global__ __launch_bounds__(128) void colsum_split(const unsigned short* __restrict__ Hh,
                                                    const unsigned short* __restrict__ Hl,
                                                    float* __restrict__ hsum, int n) {
  int f = threadIdx.x;
  int r0 = blockIdx.x * 128;
  int r1 = min(r0 + 128, n);
  float acc = 0.f;
  for (int r = r0; r < r1; ++r) {
    size_t idx = (size_t)r * 128 + f;
    acc += bfhi_f(Hh[idx]) + bfhi_f(Hl[idx]);
  }
  atomicAdd(&hsum[f], acc);
}

__global__ __launch_bounds__(128) void value_kernel(const float* __restrict__ hsum,
                                                    const float* __restrict__ w1,
                                                    const float* __restrict__ b1,
                                                    const float* __restrict__ w2,
                                                    const float* __restrict__ b2,
                                                    float* __restrict__ out) {
  __shared__ float hm[128];
  __shared__ float red[128];
  int t = threadIdx.x;
  hm[t] = hsum[t] * (1.0f / (float)N_L);
  __syncthreads();
  float acc = b1[t];
  for (int k = 0; k < 128; ++k) acc = fmaf(hm[k], w1[k * 128 + t], acc);
  red[t] = fmaxf(acc, 0.f) * w2[t];
  for (int off = 64; off > 0; off >>= 1) {
    __syncthreads();
    if (t < off) red[t] += red[t + off];
  }
  __syncthreads();
  if (t == 0) out[0] = red[0] + b2[0];
}

__global__ __launch_bounds__(64) void mask_kernel(const float* __restrict__ lp,
                                                  float* __restrict__ out) {
  int i = threadIdx.x;
  if (i < L_H) out[i] = (lp[i] > 0.5f) ? 1.0f : 0.0f;
}

// ---------------- driver ----------------

extern "C" void kernel_launch(void* const* d_in, const int* in_sizes, int n_in,
                              void* d_out, int out_size, void* d_ws, size_t ws_size,
                              hipStream_t stream) {
  const float* x      = (const float*)d_in[0];
  const int*   ei     = (const int*)d_in[1];
  const float* head_x = (const float*)d_in[2];
  const int*   hei    = (const int*)d_in[3];
  const float* enc_w1 = (const float*)d_in[4];
  const float* enc_b1 = (const float*)d_in[5];
  const float* enc_w2 = (const float*)d_in[6];
  const float* enc_b2 = (const float*)d_in[7];
  const float* gnn_w1 = (const float*)d_in[8];
  const float* gnn_b1 = (const float*)d_in[9];
  const float* gnn_w2 = (const float*)d_in[10];
  const float* gnn_b2 = (const float*)d_in[11];
  const float* lp_w1  = (const float*)d_in[12];
  const float* lp_b1  = (const float*)d_in[13];
  const float* lp_w2  = (const float*)d_in[14];
  const float* lp_b2  = (const float*)d_in[15];
  const float* hp_w1  = (const float*)d_in[16];
  const float* hp_b1  = (const float*)d_in[17];
  const float* hp_w2  = (const float*)d_in[18];
  const float* hp_b2  = (const float*)d_in[19];
  const float* v_w1   = (const float*)d_in[20];
  const float* v_b1   = (const float*)d_in[21];
  const float* v_w2   = (const float*)d_in[22];
  const float* v_b2   = (const float*)d_in[23];
  float* out = (float*)d_out;

  char* base = (char*)d_ws;
  float* SAf = (float*)(base + OFF_SAF);
  unsigned short* Hb = (unsigned short*)(base + OFF_HB);
  unsigned short* SBh = (unsigned short*)(base + OFF_SBH);
  unsigned short* SBl = (unsigned short*)(base + OFF_SBL);
  unsigned short* WTh = (unsigned short*)(base + OFF_WTH);
  unsigned short* WTl = (unsigned short*)(base + OFF_WTL);
  float* dinv_g = (float*)(base + OFF_DINV);
  float* hsum   = (float*)(base + OFF_HSUM);
  int* indeg_g  = (int*)(base + OFF_DEG);
  int* rowptr_g = (int*)(base + OFF_RP);
  unsigned* eg  = (unsigned*)(base + OFF_EG);
  int* bsum     = (int*)(base + OFF_BSUM);
  int* rank     = (int*)(base + OFF_SAF);   // overlay; consumed before enc

  const int WT_ENC1 = 0, WT_ENC2 = 32768, WT_G1 = 49152, WT_G2 = 65536,
            WT_LP = 81920, WT_HP = 98304;

  const int OUT_LP = 0, OUT_HP = N_L, OUT_MASK = N_L + N_HT, OUT_SV = N_L + N_HT + L_H;

  // ---- CSR + dinv + weight split + zero pad ----
  hipMemsetAsync(indeg_g, 0, (size_t)R_T * sizeof(int), stream);
  hipMemsetAsync(hsum, 0, 128 * sizeof(float), stream);
  hipMemsetAsync(base + OFF_ZPAD, 0, 512, stream);

  conv_weights<<<448, 256, 0, stream>>>(enc_w1, enc_w2, gnn_w1, gnn_w2, lp_w1, hp_w1,
                                        WTh, WTl);

  count_deg_all<<<(E_T + 255) / 256, 256, 0, stream>>>(ei, hei, indeg_g, rank);
  dinv_kernel<<<(R_T + 255) / 256, 256, 0, stream>>>(indeg_g, dinv_g, R_T);

  scan_block<<<(R_T + 1023) / 1024, 1024, 0, stream>>>(indeg_g, R_T, rowptr_g, bsum);
  scan_top128<<<1, 64, 0, stream>>>(bsum, (R_T + 1023) / 1024);
  scan_fix<<<(R_T + 256) / 256, 256, 0, stream>>>(rowptr_g, bsum, R_T,
                                                  (R_T + 1023) / 1024);
  fill_csr_all<<<(E_T + 255) / 256, 256, 0, stream>>>(ei, hei, rowptr_g, rank, eg);

  // ---- fused encoder + g1-mm: x -> h1 -> h2 -> G1' (scaled) ----
  enc_fused<<<R_T / 128, 256, 0, stream>>>(
      x, head_x,
      WTh + WT_ENC1, WTl + WT_ENC1,
      WTh + WT_ENC2, WTl + WT_ENC2,
      WTh + WT_G1,   WTl + WT_G1,
      enc_b1, enc_b2, dinv_g, SAf, Hb);

  // ---- GCN layer 1 aggregate ----
  agg_packed<<<R_T / 8, 256, 0, stream>>>(SAf, Hb, dinv_g, rowptr_g, eg, gnn_b1,
                                          SBh, SBl);

  // ---- GCN layer 2 ----
  mm_g<<<R_T / 128, 256, 0, stream>>>(SBh, SBl, WTh + WT_G2, WTl + WT_G2,
                                      dinv_g, SAf, Hb);
  agg_packed<<<R_T / 8, 256, 0, stream>>>(SAf, Hb, dinv_g, rowptr_g, eg, gnn_b2,
                                          SBh, SBl);

  // ---- policy heads (merged lp+hp, fused sigmoid) ----
  mm_policy<<<R_T / 128, 256, 0, stream>>>(
      SBh, SBl,
      WTh + WT_LP, WTl + WT_LP, WTh + WT_HP,
      lp_b1, hp_b1, lp_w2, hp_w2, lp_b2, hp_b2,
      out + OUT_LP, out + OUT_HP);

  // ---- value ----
  colsum_split<<<(N_L + 127) / 128, 128, 0, stream>>>(SBh, SBl, hsum, N_L);
  value_kernel<<<1, 128, 0, stream>>>(hsum, v_w1, v_b1, v_w2, v_b2, out + OUT_SV);

  // ---- mask ----
  mask_kernel<<<1, 64, 0, stream>>>(out + OUT_LP, out + OUT_MASK);
}

// Round 18
// 381.098 us; speedup vs baseline: 1.0255x; 1.0255x over previous
//
#include <hip/hip_runtime.h>
#include <math.h>

// PruningAgent r17: r16 + serial-prologue overlap via grid fusion:
//  - prep_csr = conv_weights (blocks 0..447) U count_deg_all (rest).
//  - dinv folded into scan_fix.
//  - fill_csr folded into the enc_fused dispatch (825 enc blocks + 6592
//    fill blocks backfill CU slots during enc's long blocks).
//  - rank overlay moved to SBh region (enc writes SAf; SBh first written
//    by agg, after the fused kernel completes).

typedef unsigned short ushort_t;
using short8 = __attribute__((ext_vector_type(8))) short;
using f32x4  = __attribute__((ext_vector_type(4))) float;

constexpr int N_L  = 40000;
constexpr int E_L  = 640000;
constexpr int L_H  = 8;
constexpr int N_H1 = 8192;
constexpr int E_H1 = 131072;
constexpr int N_HT = 65536;    // 8*8192
constexpr int E_HT = 1048576;  // 8*131072
constexpr int E_T  = E_L + E_HT;
constexpr int NLP  = 40064;    // layer rows padded to 128 (313*128)
constexpr int R_T  = 105600;   // NLP + N_HT
constexpr int HBASE = 40064;

constexpr int NB_ENC  = R_T / 128;            // 825
constexpr int NB_FILL = (E_T + 255) / 256;    // 6592
constexpr int NB_CONV = 448;

// workspace byte offsets
constexpr size_t OFF_SAF  = 0;                            // NLP*512 fp32 G'
constexpr size_t OFF_HB   = (size_t)NLP * 512;            // N_HT*256 bf16 G'
constexpr size_t OFF_ZPAD = OFF_HB + (size_t)N_HT * 256;  // 512 B zeros
constexpr size_t OFF_SBH  = OFF_ZPAD + 512;               // R_T*256 (rank overlay pre-agg)
constexpr size_t OFF_SBL  = OFF_SBH + (size_t)R_T * 256;  // NLP*256
constexpr size_t OFF_WTH  = OFF_SBL + (size_t)NLP * 256;  // 229376
constexpr size_t OFF_WTL  = OFF_WTH + 229376;
constexpr size_t OFF_DINV = OFF_WTL + 229376;             // R_T*4
constexpr size_t OFF_HSUM = OFF_DINV + (size_t)R_T * 4;   // 512
constexpr size_t OFF_DEG  = OFF_HSUM + 512;               // R_T*4 indeg
constexpr size_t OFF_RP   = OFF_DEG + (size_t)R_T * 4;    // (R_T+1)*4 rowptr
constexpr size_t OFF_EG   = OFF_RP + (size_t)(R_T + 1) * 4;  // (E_T+16)*4
constexpr size_t OFF_BSUM = OFF_EG + (size_t)(E_T + 16) * 4; // 512

constexpr int ZIDX_L = (int)(OFF_ZPAD / 512);   // float4-row index of zero row
constexpr int ZIDX_H = R_T;                     // head-row index of zero row

static_assert(OFF_ZPAD % 512 == 0, "zpad alignment");

// ---------------- numeric helpers ----------------

__device__ __forceinline__ unsigned short bf16_rne(float f) {
  unsigned u = __float_as_uint(f);
  unsigned r = u + 0x7FFFu + ((u >> 16) & 1u);
  return (unsigned short)(r >> 16);
}
__device__ __forceinline__ float bfhi_f(unsigned short h) {
  return __uint_as_float((unsigned)h << 16);
}
__device__ __forceinline__ void split2(float f, unsigned short& h, unsigned short& l) {
  h = bf16_rne(f);
  l = bf16_rne(f - bfhi_f(h));
}

__device__ __forceinline__ void gload16(const void* g, void* l) {
  __builtin_amdgcn_global_load_lds((__attribute__((address_space(1))) void*)(g),
                                   (__attribute__((address_space(3))) void*)(l),
                                   16, 0, 0);
}

// ---------------- prep: conv_weights U count_deg ----------------

__global__ __launch_bounds__(256) void prep_csr(
    const float* __restrict__ w0, const float* __restrict__ w1,
    const float* __restrict__ w2, const float* __restrict__ w3,
    const float* __restrict__ w4, const float* __restrict__ w5,
    unsigned short* __restrict__ th, unsigned short* __restrict__ tl,
    const int* __restrict__ ei, const int* __restrict__ hei,
    int* __restrict__ indeg, int* __restrict__ rank) {
  if (blockIdx.x < NB_CONV) {
    int t = blockIdx.x * 256 + threadIdx.x;
    const float* src; int K, dstoff, idx;
    if (t < 32768) { src = w0; K = 256; dstoff = 0; idx = t; }
    else {
      int s = (t - 32768) >> 14;
      idx = (t - 32768) & 16383;
      K = 128;
      dstoff = 32768 + s * 16384;
      src = s == 0 ? w1 : s == 1 ? w2 : s == 2 ? w3 : s == 3 ? w4 : w5;
    }
    int k = idx >> 7, c = idx & 127;
    unsigned short h_, l_;
    split2(src[idx], h_, l_);
    th[dstoff + c * K + k] = h_;
    tl[dstoff + c * K + k] = l_;
  } else {
    int i = (blockIdx.x - NB_CONV) * 256 + threadIdx.x;
    if (i < E_L) {
      rank[i] = atomicAdd(&indeg[ei[E_L + i]], 1);
    } else if (i < E_T) {
      int t = i - E_L;
      int l = t >> 17, e = t & (E_H1 - 1);
      rank[i] = atomicAdd(&indeg[HBASE + l * N_H1 + hei[l * 2 * E_H1 + E_H1 + e]], 1);
    }
  }
}

// ---------------- scans ----------------

__global__ __launch_bounds__(1024) void scan_block(const int* __restrict__ in, int n,
                                                   int* __restrict__ out,
                                                   int* __restrict__ bsum) {
  __shared__ int s[1024];
  int t = threadIdx.x;
  int i = blockIdx.x * 1024 + t;
  int v = (i < n) ? in[i] : 0;
  s[t] = v;
  __syncthreads();
  for (int off = 1; off < 1024; off <<= 1) {
    int x = (t >= off) ? s[t - off] : 0;
    __syncthreads();
    s[t] += x;
    __syncthreads();
  }
  if (i < n) out[i] = s[t] - v;
  if (t == 1023) bsum[blockIdx.x] = s[t];
}

__global__ __launch_bounds__(64) void scan_top128(int* __restrict__ bsum, int nb) {
  int lane = threadIdx.x;
  int a = (lane < nb) ? bsum[lane] : 0;
  int b = (lane + 64 < nb) ? bsum[lane + 64] : 0;
  int ia = a;
  for (int off = 1; off < 64; off <<= 1) {
    int x = __shfl_up(ia, off);
    if (lane >= off) ia += x;
  }
  int ta = __shfl(ia, 63);
  int ib = b;
  for (int off = 1; off < 64; off <<= 1) {
    int x = __shfl_up(ib, off);
    if (lane >= off) ib += x;
  }
  int tb = __shfl(ib, 63);
  if (lane < nb) bsum[lane] = ia - a;
  if (lane + 64 < nb) bsum[lane + 64] = ta + ib - b;
  if (lane == 0) bsum[nb] = ta + tb;
}

// scan_fix + dinv fused (same index range; indeg intact)
__global__ __launch_bounds__(256) void scan_fix(int* __restrict__ rowptr,
                                                const int* __restrict__ bsum,
                                                const int* __restrict__ indeg,
                                                float* __restrict__ dinv,
                                                int n, int nb) {
  int i = blockIdx.x * 256 + threadIdx.x;
  if (i < n) {
    rowptr[i] += bsum[i >> 10];
    dinv[i] = 1.0f / sqrtf((float)(indeg[i] + 1));
  } else if (i == n) {
    rowptr[n] = bsum[nb];
  }
}

// ---------------- shared mm helpers (KC=64 chunk), SPLIT-templated -------

template <bool SPLIT>
__device__ __forceinline__ void stage_w_t(const unsigned short* Wth,
                                          const unsigned short* Wtl, int K, int kc,
                                          char* Ws_h, char* Ws_l,
                                          int wv, int rsub, int xr) {
#pragma unroll
  for (int j = 0; j < 4; ++j) {
    int q = wv * 4 + j;
    int c = q * 8 + rsub;
    size_t gb = ((size_t)c * K + kc) * 2 + (size_t)xr * 16;
    gload16((const char*)Wth + gb, Ws_h + q * 1024);
    if constexpr (SPLIT) gload16((const char*)Wtl + gb, Ws_l + q * 1024);
  }
}

template <bool SPLIT>
__device__ __forceinline__ void mfma_chunk_t(const char* As_h, const char* As_l,
                                             const char* Ws_h, const char* Ws_l,
                                             int wv, int g, int li,
                                             f32x4 acc[2][8]) {
  short8 fa_h[2][2], fa_l[2][2];
#pragma unroll
  for (int m = 0; m < 2; ++m)
#pragma unroll
    for (int ks = 0; ks < 2; ++ks) {
      int row = wv * 32 + m * 16 + li;
      int off = row * 128 + ks * 64 + g * 16;
      off ^= (row & 7) << 4;
      fa_h[m][ks] = *(const short8*)(As_h + off);
      if constexpr (SPLIT) fa_l[m][ks] = *(const short8*)(As_l + off);
    }
#pragma unroll
  for (int nh = 0; nh < 2; ++nh) {
    short8 fb_h[4][2], fb_l[4][2];
#pragma unroll
    for (int n = 0; n < 4; ++n)
#pragma unroll
      for (int ks = 0; ks < 2; ++ks) {
        int c = nh * 64 + n * 16 + li;
        int off = c * 128 + ks * 64 + g * 16;
        off ^= (c & 7) << 4;
        fb_h[n][ks] = *(const short8*)(Ws_h + off);
        if constexpr (SPLIT) fb_l[n][ks] = *(const short8*)(Ws_l + off);
      }
#pragma unroll
    for (int m = 0; m < 2; ++m)
#pragma unroll
      for (int n = 0; n < 4; ++n)
#pragma unroll
        for (int ks = 0; ks < 2; ++ks) {
          f32x4 a_ = acc[m][nh * 4 + n];
          a_ = __builtin_amdgcn_mfma_f32_16x16x32_bf16(fa_h[m][ks], fb_h[n][ks], a_, 0, 0, 0);
          if constexpr (SPLIT) {
            a_ = __builtin_amdgcn_mfma_f32_16x16x32_bf16(fa_h[m][ks], fb_l[n][ks], a_, 0, 0, 0);
            a_ = __builtin_amdgcn_mfma_f32_16x16x32_bf16(fa_l[m][ks], fb_h[n][ks], a_, 0, 0, 0);
          }
          acc[m][nh * 4 + n] = a_;
        }
  }
}

template <bool SPLIT>
__device__ __forceinline__ void write_h_slice_t(const f32x4 acc[2][8],
                                                const float* bj, int kc,
                                                char* As_h, char* As_l,
                                                int wv, int g, int li) {
#pragma unroll
  for (int m = 0; m < 2; ++m)
#pragma unroll
    for (int jj = 0; jj < 4; ++jj) {
      int j = (kc >> 4) + jj;
#pragma unroll
      for (int r = 0; r < 4; ++r) {
        float o = fmaxf(acc[m][j][r] + bj[j], 0.f);
        int row = wv * 32 + m * 16 + g * 4 + r;
        int cl = jj * 16 + li;
        int byte = row * 128 + ((((cl >> 3) ^ (row & 7)) << 4) | ((cl & 7) * 2));
        if constexpr (SPLIT) {
          unsigned short h_, l_;
          split2(o, h_, l_);
          *(unsigned short*)(As_h + byte) = h_;
          *(unsigned short*)(As_l + byte) = l_;
        } else {
          *(unsigned short*)(As_h + byte) = bf16_rne(o);
        }
      }
    }
}

// G' epilogue: layer rows -> fp32 dinv*h; head rows -> bf16 dinv*h
__device__ __forceinline__ void write_g_out(const f32x4 acc[2][8],
                                            const float* __restrict__ dinvg,
                                            float* __restrict__ G,
                                            unsigned short* __restrict__ Hb,
                                            int row0, int wv, int g, int li) {
  if (row0 < NLP) {
#pragma unroll
    for (int m = 0; m < 2; ++m)
#pragma unroll
      for (int r = 0; r < 4; ++r) {
        int rowg = row0 + wv * 32 + m * 16 + g * 4 + r;
        float dvr = dinvg[rowg];
#pragma unroll
        for (int j = 0; j < 8; ++j)
          G[(size_t)rowg * 128 + j * 16 + li] = acc[m][j][r] * dvr;
      }
  } else {
#pragma unroll
    for (int m = 0; m < 2; ++m)
#pragma unroll
      for (int r = 0; r < 4; ++r) {
        int rowg = row0 + wv * 32 + m * 16 + g * 4 + r;
        float dvr = dinvg[rowg];
        int rl = rowg - HBASE;
#pragma unroll
        for (int j = 0; j < 8; ++j)
          Hb[(size_t)rl * 128 + j * 16 + li] = bf16_rne(acc[m][j][r] * dvr);
      }
  }
}

// ---------------- fused encoder + g1 matmul (+ fill backfill blocks) ------

template <bool SPLIT>
__device__ __forceinline__ void enc_body(
    const float* __restrict__ xs, int lclamp,
    const unsigned short* __restrict__ W1h, const unsigned short* __restrict__ W1l,
    const unsigned short* __restrict__ W2h, const unsigned short* __restrict__ W2l,
    const unsigned short* __restrict__ Wgh, const unsigned short* __restrict__ Wgl,
    const float* __restrict__ b1, const float* __restrict__ b2,
    const float* __restrict__ dinvg,
    float* __restrict__ G, unsigned short* __restrict__ Hb,
    char* As_h, char* As_l, char* Ws_h, char* Ws_l,
    int tid, int wv, int g, int li, int row0, int lrow0, int rsub, int xr) {
  float bj1[8], bj2[8];
#pragma unroll
  for (int j = 0; j < 8; ++j) {
    bj1[j] = b1[j * 16 + li];
    bj2[j] = b2[j * 16 + li];
  }

  f32x4 acc1[2][8];
#pragma unroll
  for (int m = 0; m < 2; ++m)
#pragma unroll
    for (int j = 0; j < 8; ++j) acc1[m][j] = f32x4{0.f, 0.f, 0.f, 0.f};

#pragma unroll
  for (int kc = 0; kc < 256; kc += 64) {
    __syncthreads();
    stage_w_t<SPLIT>(W1h, W1l, 256, kc, Ws_h, Ws_l, wv, rsub, xr);
    {
      int r = tid >> 1, hf = tid & 1;
      int lrow = min(lrow0 + r, lclamp);
      const float* src = xs + (size_t)lrow * 256 + kc + hf * 32;
#pragma unroll
      for (int i = 0; i < 4; ++i) {
        float4 a = ((const float4*)src)[2 * i];
        float4 b = ((const float4*)src)[2 * i + 1];
        float f[8] = {a.x, a.y, a.z, a.w, b.x, b.y, b.z, b.w};
        short8 vh, vl;
#pragma unroll
        for (int e = 0; e < 8; ++e) {
          if constexpr (SPLIT) {
            unsigned short h_, l_;
            split2(f[e], h_, l_);
            vh[e] = (short)h_;
            vl[e] = (short)l_;
          } else {
            vh[e] = (short)bf16_rne(f[e]);
          }
        }
        int xu = hf * 4 + i;
        int u = r * 8 + (xu ^ (r & 7));
        *(short8*)(As_h + u * 16) = vh;
        if constexpr (SPLIT) *(short8*)(As_l + u * 16) = vl;
      }
    }
    __syncthreads();
    mfma_chunk_t<SPLIT>(As_h, As_l, Ws_h, Ws_l, wv, g, li, acc1);
  }

  f32x4 acc2[2][8];
#pragma unroll
  for (int m = 0; m < 2; ++m)
#pragma unroll
    for (int j = 0; j < 8; ++j) acc2[m][j] = f32x4{0.f, 0.f, 0.f, 0.f};

#pragma unroll
  for (int kc = 0; kc < 128; kc += 64) {
    __syncthreads();
    stage_w_t<SPLIT>(W2h, W2l, 128, kc, Ws_h, Ws_l, wv, rsub, xr);
    write_h_slice_t<SPLIT>(acc1, bj1, kc, As_h, As_l, wv, g, li);
    __syncthreads();
    mfma_chunk_t<SPLIT>(As_h, As_l, Ws_h, Ws_l, wv, g, li, acc2);
  }

  f32x4 acc3[2][8];
#pragma unroll
  for (int m = 0; m < 2; ++m)
#pragma unroll
    for (int j = 0; j < 8; ++j) acc3[m][j] = f32x4{0.f, 0.f, 0.f, 0.f};

#pragma unroll
  for (int kc = 0; kc < 128; kc += 64) {
    __syncthreads();
    stage_w_t<SPLIT>(Wgh, Wgl, 128, kc, Ws_h, Ws_l, wv, rsub, xr);
    write_h_slice_t<SPLIT>(acc2, bj2, kc, As_h, As_l, wv, g, li);
    __syncthreads();
    mfma_chunk_t<SPLIT>(As_h, As_l, Ws_h, Ws_l, wv, g, li, acc3);
  }

  write_g_out(acc3, dinvg, G, Hb, row0, wv, g, li);
}

__global__ __launch_bounds__(256, 2) void enc_fused(
    const float* __restrict__ x, const float* __restrict__ head_x,
    const unsigned short* __restrict__ W1h, const unsigned short* __restrict__ W1l,
    const unsigned short* __restrict__ W2h, const unsigned short* __restrict__ W2l,
    const unsigned short* __restrict__ Wgh, const unsigned short* __restrict__ Wgl,
    const float* __restrict__ b1, const float* __restrict__ b2,
    const float* __restrict__ dinvg,
    float* __restrict__ G, unsigned short* __restrict__ Hb,
    const int* __restrict__ ei, const int* __restrict__ hei,
    const int* __restrict__ rowptr, const int* __restrict__ rank,
    unsigned* __restrict__ eg) {
  __shared__ __align__(16) char lds[65536];

  if (blockIdx.x >= NB_ENC) {
    // ---- fill backfill blocks ----
    int i = (blockIdx.x - NB_ENC) * 256 + threadIdx.x;
    if (i < E_L) {
      int dst = ei[E_L + i];
      int src = ei[i];
      eg[rowptr[dst] + rank[i]] = (unsigned)src;
    } else if (i < E_T) {
      int t = i - E_L;
      int l = t >> 17, e = t & (E_H1 - 1);
      int b2o = l * 2 * E_H1;
      int dst = HBASE + l * N_H1 + hei[b2o + E_H1 + e];
      int src = HBASE + l * N_H1 + hei[b2o + e];
      eg[rowptr[dst] + rank[i]] = (unsigned)src;
    }
    return;
  }

  char* As_h = lds;
  char* As_l = lds + 16384;
  char* Ws_h = lds + 32768;
  char* Ws_l = lds + 49152;

  const int tid = threadIdx.x;
  const int lane = tid & 63;
  const int wv = tid >> 6;
  const int g = lane >> 4;
  const int li = lane & 15;
  const int row0 = blockIdx.x * 128;
  const int rsub = lane >> 3;
  const int xr = (lane & 7) ^ ((lane >> 3) & 7);

  if (row0 < NLP) {
    enc_body<true>(x, N_L - 1, W1h, W1l, W2h, W2l, Wgh, Wgl, b1, b2, dinvg, G, Hb,
                   As_h, As_l, Ws_h, Ws_l, tid, wv, g, li, row0, row0, rsub, xr);
  } else {
    enc_body<false>(head_x, N_HT - 1, W1h, nullptr, W2h, nullptr, Wgh, nullptr,
                    b1, b2, dinvg, G, Hb,
                    As_h, As_l, Ws_h, Ws_l, tid, wv, g, li, row0, row0 - NLP,
                    rsub, xr);
  }
}

// ---------------- MFMA matmul (g2: split/single in, scaled hybrid out) -----

template <bool SPLIT>
__device__ __forceinline__ void mm_g_body(
    const unsigned short* __restrict__ Ah, const unsigned short* __restrict__ Al,
    const unsigned short* __restrict__ Wth, const unsigned short* __restrict__ Wtl,
    char* As_h, char* As_l, char* Ws_h, char* Ws_l,
    int wv, int g, int li, int row0, int rsub, int xr, f32x4 acc[2][8]) {
  constexpr int K = 128;
#pragma unroll
  for (int kc = 0; kc < K; kc += 64) {
    __syncthreads();
    stage_w_t<SPLIT>(Wth, Wtl, K, kc, Ws_h, Ws_l, wv, rsub, xr);
#pragma unroll
    for (int j = 0; j < 4; ++j) {
      int q = wv * 4 + j;
      int r = q * 8 + rsub;
      size_t gb = ((size_t)(row0 + r) * K + kc) * 2 + (size_t)xr * 16;
      gload16((const char*)Ah + gb, As_h + q * 1024);
      if constexpr (SPLIT) gload16((const char*)Al + gb, As_l + q * 1024);
    }
    __syncthreads();
    mfma_chunk_t<SPLIT>(As_h, As_l, Ws_h, Ws_l, wv, g, li, acc);
  }
}

__global__ __launch_bounds__(256) void mm_g(
    const unsigned short* __restrict__ Ah, const unsigned short* __restrict__ Al,
    const unsigned short* __restrict__ Wth, const unsigned short* __restrict__ Wtl,
    const float* __restrict__ dinvg,
    float* __restrict__ Cf, unsigned short* __restrict__ Hb) {
  __shared__ __align__(16) char lds[65536];
  char* As_h = lds;
  char* As_l = lds + 16384;
  char* Ws_h = lds + 32768;
  char* Ws_l = lds + 49152;

  const int tid = threadIdx.x;
  const int lane = tid & 63;
  const int wv = tid >> 6;
  const int g = lane >> 4;
  const int li = lane & 15;
  const int row0 = blockIdx.x * 128;
  const int rsub = lane >> 3;
  const int xr = (lane & 7) ^ ((lane >> 3) & 7);

  f32x4 acc[2][8];
#pragma unroll
  for (int m = 0; m < 2; ++m)
#pragma unroll
    for (int j = 0; j < 8; ++j) acc[m][j] = f32x4{0.f, 0.f, 0.f, 0.f};

  if (row0 < NLP)
    mm_g_body<true>(Ah, Al, Wth, Wtl, As_h, As_l, Ws_h, Ws_l,
                    wv, g, li, row0, rsub, xr, acc);
  else
    mm_g_body<false>(Ah, nullptr, Wth, nullptr, As_h, As_l, Ws_h, Ws_l,
                     wv, g, li, row0, rsub, xr, acc);

  write_g_out(acc, dinvg, Cf, Hb, row0, wv, g, li);
}

// ---------------- fused policy matmul (lp rows<NLP, hp rows>=NLP) --------

__global__ __launch_bounds__(256) void mm_policy(
    const unsigned short* __restrict__ Ah, const unsigned short* __restrict__ Al,
    const unsigned short* __restrict__ Wth_l, const unsigned short* __restrict__ Wtl_l,
    const unsigned short* __restrict__ Wth_h,
    const float* __restrict__ b1l, const float* __restrict__ b1h,
    const float* __restrict__ w2l, const float* __restrict__ w2h,
    const float* __restrict__ b2l, const float* __restrict__ b2h,
    float* __restrict__ out_l, float* __restrict__ out_h) {
  __shared__ __align__(16) char lds[65536];
  char* As_h = lds;
  char* As_l = lds + 16384;
  char* Ws_h = lds + 32768;
  char* Ws_l = lds + 49152;

  const int tid = threadIdx.x;
  const int lane = tid & 63;
  const int wv = tid >> 6;
  const int g = lane >> 4;
  const int li = lane & 15;
  const int row0 = blockIdx.x * 128;
  const bool isl = row0 < NLP;
  const int rsub = lane >> 3;
  const int xr = (lane & 7) ^ ((lane >> 3) & 7);

  const float* bias = isl ? b1l : b1h;
  const float* pw2  = isl ? w2l : w2h;
  const float* pb2  = isl ? b2l : b2h;

  f32x4 acc[2][8];
#pragma unroll
  for (int m = 0; m < 2; ++m)
#pragma unroll
    for (int j = 0; j < 8; ++j) acc[m][j] = f32x4{0.f, 0.f, 0.f, 0.f};

  if (isl)
    mm_g_body<true>(Ah, Al, Wth_l, Wtl_l, As_h, As_l, Ws_h, Ws_l,
                    wv, g, li, row0, rsub, xr, acc);
  else
    mm_g_body<false>(Ah, nullptr, Wth_h, nullptr, As_h, As_l, Ws_h, Ws_l,
                     wv, g, li, row0, rsub, xr, acc);

  float w2c[8], bj[8];
#pragma unroll
  for (int j = 0; j < 8; ++j) {
    w2c[j] = pw2[j * 16 + li];
    bj[j]  = bias[j * 16 + li];
  }
#pragma unroll
  for (int m = 0; m < 2; ++m)
#pragma unroll
    for (int r = 0; r < 4; ++r) {
      float p = 0.f;
#pragma unroll
      for (int j = 0; j < 8; ++j) {
        float o = fmaxf(acc[m][j][r] + bj[j], 0.f);
        p = fmaf(o, w2c[j], p);
      }
      p += __shfl_xor(p, 1);
      p += __shfl_xor(p, 2);
      p += __shfl_xor(p, 4);
      p += __shfl_xor(p, 8);
      if (li == 0) {
        int rowg = row0 + wv * 32 + m * 16 + g * 4 + r;
        if (isl) {
          if (rowg < N_L) out_l[rowg] = 1.0f / (1.0f + expf(-(p + pb2[0])));
        } else {
          out_h[rowg - HBASE] = 1.0f / (1.0f + expf(-(p + pb2[0])));
        }
      }
    }
}

// ---------------- GCN aggregation (pure-add gather, rowptr CSR) ------------

__global__ __launch_bounds__(256) void agg_packed(const float* __restrict__ Hin,
                                                  const unsigned short* __restrict__ Hb,
                                                  const float* __restrict__ dinvg,
                                                  const int* __restrict__ rowptr,
                                                  const unsigned* __restrict__ eg,
                                                  const float* __restrict__ bias,
                                                  unsigned short* __restrict__ Oh,
                                                  unsigned short* __restrict__ Ol) {
  int b = blockIdx.x;                 // 13200 blocks: 5008 layer + 8192 head
  {
    int x = b & 7, j = b >> 3;        // j in [0,1650)
    b = (j < 626) ? (x * 626 + j) : (5008 + x * 1024 + (j - 626));
  }
  const int lane = threadIdx.x & 63;
  const int wv = threadIdx.x >> 6;
  const int half = lane >> 5;
  const int hl = lane & 31;
  const int v = b * 8 + wv * 2 + half;

  const float4* H4 = (const float4*)Hin;
  const ushort4* Hb4 = (const ushort4*)Hb;

  float dv = dinvg[v];
  int e0 = rowptr[v], e1 = rowptr[v + 1];
  int deg = e1 - e0;

  float4 acc;
  if (v < NLP) {
    acc = H4[(size_t)v * 32 + hl];             // G'[v]
  } else {
    ushort4 t = Hb4[(size_t)(v - HBASE) * 32 + hl];
    acc.x = bfhi_f(t.x);
    acc.y = bfhi_f(t.y);
    acc.z = bfhi_f(t.z);
    acc.w = bfhi_f(t.w);
  }

  int nb = (deg + 15) >> 4;
  int nbo = __shfl_xor(nb, 32);
  int nbmax = max(nb, nbo);

  if (v < NLP) {
    for (int t = 0; t < nbmax; ++t) {
      int e = t * 16;
      unsigned pr = 0;
      if (hl < 16 && e + hl < deg) pr = eg[e0 + e + hl];
      float4 xs[16];
#pragma unroll
      for (int i = 0; i < 16; ++i) {
        unsigned pe = (unsigned)__shfl((int)pr, (half << 5) | i);
        int u = (e + i < deg) ? (int)pe : ZIDX_L;
        xs[i] = H4[(size_t)u * 32 + hl];
      }
#pragma unroll
      for (int i = 0; i < 16; ++i) {
        acc.x += xs[i].x;
        acc.y += xs[i].y;
        acc.z += xs[i].z;
        acc.w += xs[i].w;
      }
    }
  } else {
    for (int t = 0; t < nbmax; ++t) {
      int e = t * 16;
      unsigned pr = 0;
      if (hl < 16 && e + hl < deg) pr = eg[e0 + e + hl];
      ushort4 xs[16];
#pragma unroll
      for (int i = 0; i < 16; ++i) {
        unsigned pe = (unsigned)__shfl((int)pr, (half << 5) | i);
        int u = (e + i < deg) ? (int)pe : ZIDX_H;
        xs[i] = Hb4[(size_t)(u - HBASE) * 32 + hl];
      }
#pragma unroll
      for (int i = 0; i < 16; ++i) {
        acc.x += bfhi_f(xs[i].x);
        acc.y += bfhi_f(xs[i].y);
        acc.z += bfhi_f(xs[i].z);
        acc.w += bfhi_f(xs[i].w);
      }
    }
  }

  float4 bb = ((const float4*)bias)[hl];
  acc.x = fmaxf(fmaf(dv, acc.x, bb.x), 0.f);
  acc.y = fmaxf(fmaf(dv, acc.y, bb.y), 0.f);
  acc.z = fmaxf(fmaf(dv, acc.z, bb.z), 0.f);
  acc.w = fmaxf(fmaf(dv, acc.w, bb.w), 0.f);

  if (v < NLP) {
    ushort4 th, tl;
    split2(acc.x, th.x, tl.x);
    split2(acc.y, th.y, tl.y);
    split2(acc.z, th.z, tl.z);
    split2(acc.w, th.w, tl.w);
    ((ushort4*)Oh)[(size_t)v * 32 + hl] = th;
    ((ushort4*)Ol)[(size_t)v * 32 + hl] = tl;
  } else {
    ushort4 th;
    th.x = bf16_rne(acc.x);
    th.y = bf16_rne(acc.y);
    th.z = bf16_rne(acc.z);
    th.w = bf16_rne(acc.w);
    ((ushort4*)Oh)[(size_t)v * 32 + hl] = th;
  }
}

// ---------------- value head ----------------

__global__ __launch_bounds__(128) void colsum_split(const unsigned short* __restrict__ Hh,
                                                    const unsigned short* __restrict__ Hl,
                                                    float* __restrict__ hsum, int n) {
  int f = threadIdx.x;
  int r0 = blockIdx.x * 128;
  int r1 = min(r0 + 128, n);
  float acc = 0.f;
  for (int r = r0; r < r1; ++r) {
    size_t idx = (size_t)r * 128 + f;
    acc += bfhi_f(Hh[idx]) + bfhi_f(Hl[idx]);
  }
  atomicAdd(&hsum[f], acc);
}

__global__ __launch_bounds__(128) void value_kernel(const float* __restrict__ hsum,
                                                    const float* __restrict__ w1,
                                                    const float* __restrict__ b1,
                                                    const float* __restrict__ w2,
                                                    const float* __restrict__ b2,
                                                    float* __restrict__ out) {
  __shared__ float hm[128];
  __shared__ float red[128];
  int t = threadIdx.x;
  hm[t] = hsum[t] * (1.0f / (float)N_L);
  __syncthreads();
  float acc = b1[t];
  for (int k = 0; k < 128; ++k) acc = fmaf(hm[k], w1[k * 128 + t], acc);
  red[t] = fmaxf(acc, 0.f) * w2[t];
  for (int off = 64; off > 0; off >>= 1) {
    __syncthreads();
    if (t < off) red[t] += red[t + off];
  }
  __syncthreads();
  if (t == 0) out[0] = red[0] + b2[0];
}

__global__ __launch_bounds__(64) void mask_kernel(const float* __restrict__ lp,
                                                  float* __restrict__ out) {
  int i = threadIdx.x;
  if (i < L_H) out[i] = (lp[i] > 0.5f) ? 1.0f : 0.0f;
}

// ---------------- driver ----------------

extern "C" void kernel_launch(void* const* d_in, const int* in_sizes, int n_in,
                              void* d_out, int out_size, void* d_ws, size_t ws_size,
                              hipStream_t stream) {
  const float* x      = (const float*)d_in[0];
  const int*   ei     = (const int*)d_in[1];
  const float* head_x = (const float*)d_in[2];
  const int*   hei    = (const int*)d_in[3];
  const float* enc_w1 = (const float*)d_in[4];
  const float* enc_b1 = (const float*)d_in[5];
  const float* enc_w2 = (const float*)d_in[6];
  const float* enc_b2 = (const float*)d_in[7];
  const float* gnn_w1 = (const float*)d_in[8];
  const float* gnn_b1 = (const float*)d_in[9];
  const float* gnn_w2 = (const float*)d_in[10];
  const float* gnn_b2 = (const float*)d_in[11];
  const float* lp_w1  = (const float*)d_in[12];
  const float* lp_b1  = (const float*)d_in[13];
  const float* lp_w2  = (const float*)d_in[14];
  const float* lp_b2  = (const float*)d_in[15];
  const float* hp_w1  = (const float*)d_in[16];
  const float* hp_b1  = (const float*)d_in[17];
  const float* hp_w2  = (const float*)d_in[18];
  const float* hp_b2  = (const float*)d_in[19];
  const float* v_w1   = (const float*)d_in[20];
  const float* v_b1   = (const float*)d_in[21];
  const float* v_w2   = (const float*)d_in[22];
  const float* v_b2   = (const float*)d_in[23];
  float* out = (float*)d_out;

  char* base = (char*)d_ws;
  float* SAf = (float*)(base + OFF_SAF);
  unsigned short* Hb = (unsigned short*)(base + OFF_HB);
  unsigned short* SBh = (unsigned short*)(base + OFF_SBH);
  unsigned short* SBl = (unsigned short*)(base + OFF_SBL);
  unsigned short* WTh = (unsigned short*)(base + OFF_WTH);
  unsigned short* WTl = (unsigned short*)(base + OFF_WTL);
  float* dinv_g = (float*)(base + OFF_DINV);
  float* hsum   = (float*)(base + OFF_HSUM);
  int* indeg_g  = (int*)(base + OFF_DEG);
  int* rowptr_g = (int*)(base + OFF_RP);
  unsigned* eg  = (unsigned*)(base + OFF_EG);
  int* bsum     = (int*)(base + OFF_BSUM);
  int* rank     = (int*)(base + OFF_SBH);   // overlay; consumed by fill blocks
                                            // inside enc_fused, before agg
                                            // writes SBh

  const int WT_ENC1 = 0, WT_ENC2 = 32768, WT_G1 = 49152, WT_G2 = 65536,
            WT_LP = 81920, WT_HP = 98304;

  const int OUT_LP = 0, OUT_HP = N_L, OUT_MASK = N_L + N_HT, OUT_SV = N_L + N_HT + L_H;

  // ---- CSR + dinv + weight split + zero pad ----
  hipMemsetAsync(indeg_g, 0, (size_t)R_T * sizeof(int), stream);
  hipMemsetAsync(hsum, 0, 128 * sizeof(float), stream);
  hipMemsetAsync(base + OFF_ZPAD, 0, 512, stream);

  prep_csr<<<NB_CONV + NB_FILL, 256, 0, stream>>>(
      enc_w1, enc_w2, gnn_w1, gnn_w2, lp_w1, hp_w1, WTh, WTl,
      ei, hei, indeg_g, rank);

  scan_block<<<(R_T + 1023) / 1024, 1024, 0, stream>>>(indeg_g, R_T, rowptr_g, bsum);
  scan_top128<<<1, 64, 0, stream>>>(bsum, (R_T + 1023) / 1024);
  scan_fix<<<(R_T + 256) / 256, 256, 0, stream>>>(rowptr_g, bsum, indeg_g, dinv_g,
                                                  R_T, (R_T + 1023) / 1024);

  // ---- fused encoder + g1-mm (+ fill backfill blocks) ----
  enc_fused<<<NB_ENC + NB_FILL, 256, 0, stream>>>(
      x, head_x,
      WTh + WT_ENC1, WTl + WT_ENC1,
      WTh + WT_ENC2, WTl + WT_ENC2,
      WTh + WT_G1,   WTl + WT_G1,
      enc_b1, enc_b2, dinv_g, SAf, Hb,
      ei, hei, rowptr_g, rank, eg);

  // ---- GCN layer 1 aggregate ----
  agg_packed<<<R_T / 8, 256, 0, stream>>>(SAf, Hb, dinv_g, rowptr_g, eg, gnn_b1,
                                          SBh, SBl);

  // ---- GCN layer 2 ----
  mm_g<<<R_T / 128, 256, 0, stream>>>(SBh, SBl, WTh + WT_G2, WTl + WT_G2,
                                      dinv_g, SAf, Hb);
  agg_packed<<<R_T / 8, 256, 0, stream>>>(SAf, Hb, dinv_g, rowptr_g, eg, gnn_b2,
                                          SBh, SBl);

  // ---- policy heads (merged lp+hp, fused sigmoid) ----
  mm_policy<<<R_T / 128, 256, 0, stream>>>(
      SBh, SBl,
      WTh + WT_LP, WTl + WT_LP, WTh + WT_HP,
      lp_b1, hp_b1, lp_w2, hp_w2, lp_b2, hp_b2,
      out + OUT_LP, out + OUT_HP);

  // ---- value ----
  colsum_split<<<(N_L + 127) / 128, 128, 0, stream>>>(SBh, SBl, hsum, N_L);
  value_kernel<<<1, 128, 0, stream>>>(hsum, v_w1, v_b1, v_w2, v_b2, out + OUT_SV);

  // ---- mask ----
  mask_kernel<<<1, 64, 0, stream>>>(out + OUT_LP, out + OUT_MASK);
}

// Round 19
// 372.667 us; speedup vs baseline: 1.0487x; 1.0226x over previous
//
#include <hip/hip_runtime.h>
#include <math.h>

// PruningAgent r18: r17 +
//  - eg stored as u16 LOCAL ids (layer src<40000, head src-HBASE<65536):
//    halves fill scatter payload + agg eg stream; head agg drops -HBASE.
//  - colsum_split backfilled into mm_policy dispatch (313 extra blocks).

typedef unsigned short ushort_t;
using short8 = __attribute__((ext_vector_type(8))) short;
using f32x4  = __attribute__((ext_vector_type(4))) float;

constexpr int N_L  = 40000;
constexpr int E_L  = 640000;
constexpr int L_H  = 8;
constexpr int N_H1 = 8192;
constexpr int E_H1 = 131072;
constexpr int N_HT = 65536;    // 8*8192
constexpr int E_HT = 1048576;  // 8*131072
constexpr int E_T  = E_L + E_HT;
constexpr int NLP  = 40064;    // layer rows padded to 128 (313*128)
constexpr int R_T  = 105600;   // NLP + N_HT
constexpr int HBASE = 40064;

constexpr int NB_ENC  = R_T / 128;            // 825
constexpr int NB_FILL = (E_T + 255) / 256;    // 6592
constexpr int NB_CONV = 448;
constexpr int NB_POL  = R_T / 128;            // 825
constexpr int NB_CSUM = (N_L + 127) / 128;    // 313

// workspace byte offsets
constexpr size_t OFF_SAF  = 0;                            // NLP*512 fp32 G'
constexpr size_t OFF_HB   = (size_t)NLP * 512;            // N_HT*256 bf16 G'
constexpr size_t OFF_ZPAD = OFF_HB + (size_t)N_HT * 256;  // 512 B zeros
constexpr size_t OFF_SBH  = OFF_ZPAD + 512;               // R_T*256 (rank overlay pre-agg)
constexpr size_t OFF_SBL  = OFF_SBH + (size_t)R_T * 256;  // NLP*256
constexpr size_t OFF_WTH  = OFF_SBL + (size_t)NLP * 256;  // 229376
constexpr size_t OFF_WTL  = OFF_WTH + 229376;
constexpr size_t OFF_DINV = OFF_WTL + 229376;             // R_T*4
constexpr size_t OFF_HSUM = OFF_DINV + (size_t)R_T * 4;   // 512
constexpr size_t OFF_DEG  = OFF_HSUM + 512;               // R_T*4 indeg
constexpr size_t OFF_RP   = OFF_DEG + (size_t)R_T * 4;    // (R_T+1)*4 rowptr
constexpr size_t OFF_EG   = OFF_RP + (size_t)(R_T + 1) * 4;  // (E_T+32)*2 u16
constexpr size_t OFF_BSUM = OFF_EG + (size_t)(E_T + 32) * 2; // 512

constexpr int ZIDX_L = (int)(OFF_ZPAD / 512);   // float4-row index of zero row
constexpr int ZIDX_H = N_HT;                    // Hb local row N_HT = ZPAD start

static_assert(OFF_ZPAD % 512 == 0, "zpad alignment");

// ---------------- numeric helpers ----------------

__device__ __forceinline__ unsigned short bf16_rne(float f) {
  unsigned u = __float_as_uint(f);
  unsigned r = u + 0x7FFFu + ((u >> 16) & 1u);
  return (unsigned short)(r >> 16);
}
__device__ __forceinline__ float bfhi_f(unsigned short h) {
  return __uint_as_float((unsigned)h << 16);
}
__device__ __forceinline__ void split2(float f, unsigned short& h, unsigned short& l) {
  h = bf16_rne(f);
  l = bf16_rne(f - bfhi_f(h));
}

__device__ __forceinline__ void gload16(const void* g, void* l) {
  __builtin_amdgcn_global_load_lds((__attribute__((address_space(1))) void*)(g),
                                   (__attribute__((address_space(3))) void*)(l),
                                   16, 0, 0);
}

// ---------------- prep: conv_weights U count_deg ----------------

__global__ __launch_bounds__(256) void prep_csr(
    const float* __restrict__ w0, const float* __restrict__ w1,
    const float* __restrict__ w2, const float* __restrict__ w3,
    const float* __restrict__ w4, const float* __restrict__ w5,
    unsigned short* __restrict__ th, unsigned short* __restrict__ tl,
    const int* __restrict__ ei, const int* __restrict__ hei,
    int* __restrict__ indeg, int* __restrict__ rank) {
  if (blockIdx.x < NB_CONV) {
    int t = blockIdx.x * 256 + threadIdx.x;
    const float* src; int K, dstoff, idx;
    if (t < 32768) { src = w0; K = 256; dstoff = 0; idx = t; }
    else {
      int s = (t - 32768) >> 14;
      idx = (t - 32768) & 16383;
      K = 128;
      dstoff = 32768 + s * 16384;
      src = s == 0 ? w1 : s == 1 ? w2 : s == 2 ? w3 : s == 3 ? w4 : w5;
    }
    int k = idx >> 7, c = idx & 127;
    unsigned short h_, l_;
    split2(src[idx], h_, l_);
    th[dstoff + c * K + k] = h_;
    tl[dstoff + c * K + k] = l_;
  } else {
    int i = (blockIdx.x - NB_CONV) * 256 + threadIdx.x;
    if (i < E_L) {
      rank[i] = atomicAdd(&indeg[ei[E_L + i]], 1);
    } else if (i < E_T) {
      int t = i - E_L;
      int l = t >> 17, e = t & (E_H1 - 1);
      rank[i] = atomicAdd(&indeg[HBASE + l * N_H1 + hei[l * 2 * E_H1 + E_H1 + e]], 1);
    }
  }
}

// ---------------- scans ----------------

__global__ __launch_bounds__(1024) void scan_block(const int* __restrict__ in, int n,
                                                   int* __restrict__ out,
                                                   int* __restrict__ bsum) {
  __shared__ int s[1024];
  int t = threadIdx.x;
  int i = blockIdx.x * 1024 + t;
  int v = (i < n) ? in[i] : 0;
  s[t] = v;
  __syncthreads();
  for (int off = 1; off < 1024; off <<= 1) {
    int x = (t >= off) ? s[t - off] : 0;
    __syncthreads();
    s[t] += x;
    __syncthreads();
  }
  if (i < n) out[i] = s[t] - v;
  if (t == 1023) bsum[blockIdx.x] = s[t];
}

__global__ __launch_bounds__(64) void scan_top128(int* __restrict__ bsum, int nb) {
  int lane = threadIdx.x;
  int a = (lane < nb) ? bsum[lane] : 0;
  int b = (lane + 64 < nb) ? bsum[lane + 64] : 0;
  int ia = a;
  for (int off = 1; off < 64; off <<= 1) {
    int x = __shfl_up(ia, off);
    if (lane >= off) ia += x;
  }
  int ta = __shfl(ia, 63);
  int ib = b;
  for (int off = 1; off < 64; off <<= 1) {
    int x = __shfl_up(ib, off);
    if (lane >= off) ib += x;
  }
  int tb = __shfl(ib, 63);
  if (lane < nb) bsum[lane] = ia - a;
  if (lane + 64 < nb) bsum[lane + 64] = ta + ib - b;
  if (lane == 0) bsum[nb] = ta + tb;
}

// scan_fix + dinv fused
__global__ __launch_bounds__(256) void scan_fix(int* __restrict__ rowptr,
                                                const int* __restrict__ bsum,
                                                const int* __restrict__ indeg,
                                                float* __restrict__ dinv,
                                                int n, int nb) {
  int i = blockIdx.x * 256 + threadIdx.x;
  if (i < n) {
    rowptr[i] += bsum[i >> 10];
    dinv[i] = 1.0f / sqrtf((float)(indeg[i] + 1));
  } else if (i == n) {
    rowptr[n] = bsum[nb];
  }
}

// ---------------- shared mm helpers (KC=64 chunk), SPLIT-templated -------

template <bool SPLIT>
__device__ __forceinline__ void stage_w_t(const unsigned short* Wth,
                                          const unsigned short* Wtl, int K, int kc,
                                          char* Ws_h, char* Ws_l,
                                          int wv, int rsub, int xr) {
#pragma unroll
  for (int j = 0; j < 4; ++j) {
    int q = wv * 4 + j;
    int c = q * 8 + rsub;
    size_t gb = ((size_t)c * K + kc) * 2 + (size_t)xr * 16;
    gload16((const char*)Wth + gb, Ws_h + q * 1024);
    if constexpr (SPLIT) gload16((const char*)Wtl + gb, Ws_l + q * 1024);
  }
}

template <bool SPLIT>
__device__ __forceinline__ void mfma_chunk_t(const char* As_h, const char* As_l,
                                             const char* Ws_h, const char* Ws_l,
                                             int wv, int g, int li,
                                             f32x4 acc[2][8]) {
  short8 fa_h[2][2], fa_l[2][2];
#pragma unroll
  for (int m = 0; m < 2; ++m)
#pragma unroll
    for (int ks = 0; ks < 2; ++ks) {
      int row = wv * 32 + m * 16 + li;
      int off = row * 128 + ks * 64 + g * 16;
      off ^= (row & 7) << 4;
      fa_h[m][ks] = *(const short8*)(As_h + off);
      if constexpr (SPLIT) fa_l[m][ks] = *(const short8*)(As_l + off);
    }
#pragma unroll
  for (int nh = 0; nh < 2; ++nh) {
    short8 fb_h[4][2], fb_l[4][2];
#pragma unroll
    for (int n = 0; n < 4; ++n)
#pragma unroll
      for (int ks = 0; ks < 2; ++ks) {
        int c = nh * 64 + n * 16 + li;
        int off = c * 128 + ks * 64 + g * 16;
        off ^= (c & 7) << 4;
        fb_h[n][ks] = *(const short8*)(Ws_h + off);
        if constexpr (SPLIT) fb_l[n][ks] = *(const short8*)(Ws_l + off);
      }
#pragma unroll
    for (int m = 0; m < 2; ++m)
#pragma unroll
      for (int n = 0; n < 4; ++n)
#pragma unroll
        for (int ks = 0; ks < 2; ++ks) {
          f32x4 a_ = acc[m][nh * 4 + n];
          a_ = __builtin_amdgcn_mfma_f32_16x16x32_bf16(fa_h[m][ks], fb_h[n][ks], a_, 0, 0, 0);
          if constexpr (SPLIT) {
            a_ = __builtin_amdgcn_mfma_f32_16x16x32_bf16(fa_h[m][ks], fb_l[n][ks], a_, 0, 0, 0);
            a_ = __builtin_amdgcn_mfma_f32_16x16x32_bf16(fa_l[m][ks], fb_h[n][ks], a_, 0, 0, 0);
          }
          acc[m][nh * 4 + n] = a_;
        }
  }
}

template <bool SPLIT>
__device__ __forceinline__ void write_h_slice_t(const f32x4 acc[2][8],
                                                const float* bj, int kc,
                                                char* As_h, char* As_l,
                                                int wv, int g, int li) {
#pragma unroll
  for (int m = 0; m < 2; ++m)
#pragma unroll
    for (int jj = 0; jj < 4; ++jj) {
      int j = (kc >> 4) + jj;
#pragma unroll
      for (int r = 0; r < 4; ++r) {
        float o = fmaxf(acc[m][j][r] + bj[j], 0.f);
        int row = wv * 32 + m * 16 + g * 4 + r;
        int cl = jj * 16 + li;
        int byte = row * 128 + ((((cl >> 3) ^ (row & 7)) << 4) | ((cl & 7) * 2));
        if constexpr (SPLIT) {
          unsigned short h_, l_;
          split2(o, h_, l_);
          *(unsigned short*)(As_h + byte) = h_;
          *(unsigned short*)(As_l + byte) = l_;
        } else {
          *(unsigned short*)(As_h + byte) = bf16_rne(o);
        }
      }
    }
}

// G' epilogue: layer rows -> fp32 dinv*h; head rows -> bf16 dinv*h
__device__ __forceinline__ void write_g_out(const f32x4 acc[2][8],
                                            const float* __restrict__ dinvg,
                                            float* __restrict__ G,
                                            unsigned short* __restrict__ Hb,
                                            int row0, int wv, int g, int li) {
  if (row0 < NLP) {
#pragma unroll
    for (int m = 0; m < 2; ++m)
#pragma unroll
      for (int r = 0; r < 4; ++r) {
        int rowg = row0 + wv * 32 + m * 16 + g * 4 + r;
        float dvr = dinvg[rowg];
#pragma unroll
        for (int j = 0; j < 8; ++j)
          G[(size_t)rowg * 128 + j * 16 + li] = acc[m][j][r] * dvr;
      }
  } else {
#pragma unroll
    for (int m = 0; m < 2; ++m)
#pragma unroll
      for (int r = 0; r < 4; ++r) {
        int rowg = row0 + wv * 32 + m * 16 + g * 4 + r;
        float dvr = dinvg[rowg];
        int rl = rowg - HBASE;
#pragma unroll
        for (int j = 0; j < 8; ++j)
          Hb[(size_t)rl * 128 + j * 16 + li] = bf16_rne(acc[m][j][r] * dvr);
      }
  }
}

// ---------------- fused encoder + g1 matmul (+ fill backfill blocks) ------

template <bool SPLIT>
__device__ __forceinline__ void enc_body(
    const float* __restrict__ xs, int lclamp,
    const unsigned short* __restrict__ W1h, const unsigned short* __restrict__ W1l,
    const unsigned short* __restrict__ W2h, const unsigned short* __restrict__ W2l,
    const unsigned short* __restrict__ Wgh, const unsigned short* __restrict__ Wgl,
    const float* __restrict__ b1, const float* __restrict__ b2,
    const float* __restrict__ dinvg,
    float* __restrict__ G, unsigned short* __restrict__ Hb,
    char* As_h, char* As_l, char* Ws_h, char* Ws_l,
    int tid, int wv, int g, int li, int row0, int lrow0, int rsub, int xr) {
  float bj1[8], bj2[8];
#pragma unroll
  for (int j = 0; j < 8; ++j) {
    bj1[j] = b1[j * 16 + li];
    bj2[j] = b2[j * 16 + li];
  }

  f32x4 acc1[2][8];
#pragma unroll
  for (int m = 0; m < 2; ++m)
#pragma unroll
    for (int j = 0; j < 8; ++j) acc1[m][j] = f32x4{0.f, 0.f, 0.f, 0.f};

#pragma unroll
  for (int kc = 0; kc < 256; kc += 64) {
    __syncthreads();
    stage_w_t<SPLIT>(W1h, W1l, 256, kc, Ws_h, Ws_l, wv, rsub, xr);
    {
      int r = tid >> 1, hf = tid & 1;
      int lrow = min(lrow0 + r, lclamp);
      const float* src = xs + (size_t)lrow * 256 + kc + hf * 32;
#pragma unroll
      for (int i = 0; i < 4; ++i) {
        float4 a = ((const float4*)src)[2 * i];
        float4 b = ((const float4*)src)[2 * i + 1];
        float f[8] = {a.x, a.y, a.z, a.w, b.x, b.y, b.z, b.w};
        short8 vh, vl;
#pragma unroll
        for (int e = 0; e < 8; ++e) {
          if constexpr (SPLIT) {
            unsigned short h_, l_;
            split2(f[e], h_, l_);
            vh[e] = (short)h_;
            vl[e] = (short)l_;
          } else {
            vh[e] = (short)bf16_rne(f[e]);
          }
        }
        int xu = hf * 4 + i;
        int u = r * 8 + (xu ^ (r & 7));
        *(short8*)(As_h + u * 16) = vh;
        if constexpr (SPLIT) *(short8*)(As_l + u * 16) = vl;
      }
    }
    __syncthreads();
    mfma_chunk_t<SPLIT>(As_h, As_l, Ws_h, Ws_l, wv, g, li, acc1);
  }

  f32x4 acc2[2][8];
#pragma unroll
  for (int m = 0; m < 2; ++m)
#pragma unroll
    for (int j = 0; j < 8; ++j) acc2[m][j] = f32x4{0.f, 0.f, 0.f, 0.f};

#pragma unroll
  for (int kc = 0; kc < 128; kc += 64) {
    __syncthreads();
    stage_w_t<SPLIT>(W2h, W2l, 128, kc, Ws_h, Ws_l, wv, rsub, xr);
    write_h_slice_t<SPLIT>(acc1, bj1, kc, As_h, As_l, wv, g, li);
    __syncthreads();
    mfma_chunk_t<SPLIT>(As_h, As_l, Ws_h, Ws_l, wv, g, li, acc2);
  }

  f32x4 acc3[2][8];
#pragma unroll
  for (int m = 0; m < 2; ++m)
#pragma unroll
    for (int j = 0; j < 8; ++j) acc3[m][j] = f32x4{0.f, 0.f, 0.f, 0.f};

#pragma unroll
  for (int kc = 0; kc < 128; kc += 64) {
    __syncthreads();
    stage_w_t<SPLIT>(Wgh, Wgl, 128, kc, Ws_h, Ws_l, wv, rsub, xr);
    write_h_slice_t<SPLIT>(acc2, bj2, kc, As_h, As_l, wv, g, li);
    __syncthreads();
    mfma_chunk_t<SPLIT>(As_h, As_l, Ws_h, Ws_l, wv, g, li, acc3);
  }

  write_g_out(acc3, dinvg, G, Hb, row0, wv, g, li);
}

__global__ __launch_bounds__(256, 2) void enc_fused(
    const float* __restrict__ x, const float* __restrict__ head_x,
    const unsigned short* __restrict__ W1h, const unsigned short* __restrict__ W1l,
    const unsigned short* __restrict__ W2h, const unsigned short* __restrict__ W2l,
    const unsigned short* __restrict__ Wgh, const unsigned short* __restrict__ Wgl,
    const float* __restrict__ b1, const float* __restrict__ b2,
    const float* __restrict__ dinvg,
    float* __restrict__ G, unsigned short* __restrict__ Hb,
    const int* __restrict__ ei, const int* __restrict__ hei,
    const int* __restrict__ rowptr, const int* __restrict__ rank,
    unsigned short* __restrict__ eg) {
  __shared__ __align__(16) char lds[65536];

  if (blockIdx.x >= NB_ENC) {
    // ---- fill backfill blocks (u16 local ids) ----
    int i = (blockIdx.x - NB_ENC) * 256 + threadIdx.x;
    if (i < E_L) {
      int dst = ei[E_L + i];
      int src = ei[i];                       // local == global for layer
      eg[rowptr[dst] + rank[i]] = (unsigned short)src;
    } else if (i < E_T) {
      int t = i - E_L;
      int l = t >> 17, e = t & (E_H1 - 1);
      int b2o = l * 2 * E_H1;
      int dst = HBASE + l * N_H1 + hei[b2o + E_H1 + e];
      int srcl = l * N_H1 + hei[b2o + e];    // head-local id
      eg[rowptr[dst] + rank[i]] = (unsigned short)srcl;
    }
    return;
  }

  char* As_h = lds;
  char* As_l = lds + 16384;
  char* Ws_h = lds + 32768;
  char* Ws_l = lds + 49152;

  const int tid = threadIdx.x;
  const int lane = tid & 63;
  const int wv = tid >> 6;
  const int g = lane >> 4;
  const int li = lane & 15;
  const int row0 = blockIdx.x * 128;
  const int rsub = lane >> 3;
  const int xr = (lane & 7) ^ ((lane >> 3) & 7);

  if (row0 < NLP) {
    enc_body<true>(x, N_L - 1, W1h, W1l, W2h, W2l, Wgh, Wgl, b1, b2, dinvg, G, Hb,
                   As_h, As_l, Ws_h, Ws_l, tid, wv, g, li, row0, row0, rsub, xr);
  } else {
    enc_body<false>(head_x, N_HT - 1, W1h, nullptr, W2h, nullptr, Wgh, nullptr,
                    b1, b2, dinvg, G, Hb,
                    As_h, As_l, Ws_h, Ws_l, tid, wv, g, li, row0, row0 - NLP,
                    rsub, xr);
  }
}

// ---------------- MFMA matmul (g2: split/single in, scaled hybrid out) -----

template <bool SPLIT>
__device__ __forceinline__ void mm_g_body(
    const unsigned short* __restrict__ Ah, const unsigned short* __restrict__ Al,
    const unsigned short* __restrict__ Wth, const unsigned short* __restrict__ Wtl,
    char* As_h, char* As_l, char* Ws_h, char* Ws_l,
    int wv, int g, int li, int row0, int rsub, int xr, f32x4 acc[2][8]) {
  constexpr int K = 128;
#pragma unroll
  for (int kc = 0; kc < K; kc += 64) {
    __syncthreads();
    stage_w_t<SPLIT>(Wth, Wtl, K, kc, Ws_h, Ws_l, wv, rsub, xr);
#pragma unroll
    for (int j = 0; j < 4; ++j) {
      int q = wv * 4 + j;
      int r = q * 8 + rsub;
      size_t gb = ((size_t)(row0 + r) * K + kc) * 2 + (size_t)xr * 16;
      gload16((const char*)Ah + gb, As_h + q * 1024);
      if constexpr (SPLIT) gload16((const char*)Al + gb, As_l + q * 1024);
    }
    __syncthreads();
    mfma_chunk_t<SPLIT>(As_h, As_l, Ws_h, Ws_l, wv, g, li, acc);
  }
}

__global__ __launch_bounds__(256) void mm_g(
    const unsigned short* __restrict__ Ah, const unsigned short* __restrict__ Al,
    const unsigned short* __restrict__ Wth, const unsigned short* __restrict__ Wtl,
    const float* __restrict__ dinvg,
    float* __restrict__ Cf, unsigned short* __restrict__ Hb) {
  __shared__ __align__(16) char lds[65536];
  char* As_h = lds;
  char* As_l = lds + 16384;
  char* Ws_h = lds + 32768;
  char* Ws_l = lds + 49152;

  const int tid = threadIdx.x;
  const int lane = tid & 63;
  const int wv = tid >> 6;
  const int g = lane >> 4;
  const int li = lane & 15;
  const int row0 = blockIdx.x * 128;
  const int rsub = lane >> 3;
  const int xr = (lane & 7) ^ ((lane >> 3) & 7);

  f32x4 acc[2][8];
#pragma unroll
  for (int m = 0; m < 2; ++m)
#pragma unroll
    for (int j = 0; j < 8; ++j) acc[m][j] = f32x4{0.f, 0.f, 0.f, 0.f};

  if (row0 < NLP)
    mm_g_body<true>(Ah, Al, Wth, Wtl, As_h, As_l, Ws_h, Ws_l,
                    wv, g, li, row0, rsub, xr, acc);
  else
    mm_g_body<false>(Ah, nullptr, Wth, nullptr, As_h, As_l, Ws_h, Ws_l,
                     wv, g, li, row0, rsub, xr, acc);

  write_g_out(acc, dinvg, Cf, Hb, row0, wv, g, li);
}

// ---------------- fused policy matmul (+ colsum backfill blocks) ----------

__global__ __launch_bounds__(256) void mm_policy(
    const unsigned short* __restrict__ Ah, const unsigned short* __restrict__ Al,
    const unsigned short* __restrict__ Wth_l, const unsigned short* __restrict__ Wtl_l,
    const unsigned short* __restrict__ Wth_h,
    const float* __restrict__ b1l, const float* __restrict__ b1h,
    const float* __restrict__ w2l, const float* __restrict__ w2h,
    const float* __restrict__ b2l, const float* __restrict__ b2h,
    float* __restrict__ out_l, float* __restrict__ out_h,
    float* __restrict__ hsum) {
  __shared__ __align__(16) char lds[65536];

  if (blockIdx.x >= NB_POL) {
    // ---- colsum backfill: partial column sums of SB (layer rows) ----
    int cb = blockIdx.x - NB_POL;
    int f = threadIdx.x & 127;
    int half = threadIdx.x >> 7;
    int r0 = cb * 128 + half * 64;
    int r1 = min(r0 + 64, N_L);
    float acc = 0.f;
    for (int r = r0; r < r1; ++r) {
      size_t idx = (size_t)r * 128 + f;
      acc += bfhi_f(Ah[idx]) + bfhi_f(Al[idx]);
    }
    atomicAdd(&hsum[f], acc);
    return;
  }

  char* As_h = lds;
  char* As_l = lds + 16384;
  char* Ws_h = lds + 32768;
  char* Ws_l = lds + 49152;

  const int tid = threadIdx.x;
  const int lane = tid & 63;
  const int wv = tid >> 6;
  const int g = lane >> 4;
  const int li = lane & 15;
  const int row0 = blockIdx.x * 128;
  const bool isl = row0 < NLP;
  const int rsub = lane >> 3;
  const int xr = (lane & 7) ^ ((lane >> 3) & 7);

  const float* bias = isl ? b1l : b1h;
  const float* pw2  = isl ? w2l : w2h;
  const float* pb2  = isl ? b2l : b2h;

  f32x4 acc[2][8];
#pragma unroll
  for (int m = 0; m < 2; ++m)
#pragma unroll
    for (int j = 0; j < 8; ++j) acc[m][j] = f32x4{0.f, 0.f, 0.f, 0.f};

  if (isl)
    mm_g_body<true>(Ah, Al, Wth_l, Wtl_l, As_h, As_l, Ws_h, Ws_l,
                    wv, g, li, row0, rsub, xr, acc);
  else
    mm_g_body<false>(Ah, nullptr, Wth_h, nullptr, As_h, As_l, Ws_h, Ws_l,
                     wv, g, li, row0, rsub, xr, acc);

  float w2c[8], bj[8];
#pragma unroll
  for (int j = 0; j < 8; ++j) {
    w2c[j] = pw2[j * 16 + li];
    bj[j]  = bias[j * 16 + li];
  }
#pragma unroll
  for (int m = 0; m < 2; ++m)
#pragma unroll
    for (int r = 0; r < 4; ++r) {
      float p = 0.f;
#pragma unroll
      for (int j = 0; j < 8; ++j) {
        float o = fmaxf(acc[m][j][r] + bj[j], 0.f);
        p = fmaf(o, w2c[j], p);
      }
      p += __shfl_xor(p, 1);
      p += __shfl_xor(p, 2);
      p += __shfl_xor(p, 4);
      p += __shfl_xor(p, 8);
      if (li == 0) {
        int rowg = row0 + wv * 32 + m * 16 + g * 4 + r;
        if (isl) {
          if (rowg < N_L) out_l[rowg] = 1.0f / (1.0f + expf(-(p + pb2[0])));
        } else {
          out_h[rowg - HBASE] = 1.0f / (1.0f + expf(-(p + pb2[0])));
        }
      }
    }
}

// ---------------- GCN aggregation (pure-add gather, rowptr CSR, u16 eg) ----

__global__ __launch_bounds__(256) void agg_packed(const float* __restrict__ Hin,
                                                  const unsigned short* __restrict__ Hb,
                                                  const float* __restrict__ dinvg,
                                                  const int* __restrict__ rowptr,
                                                  const unsigned short* __restrict__ eg,
                                                  const float* __restrict__ bias,
                                                  unsigned short* __restrict__ Oh,
                                                  unsigned short* __restrict__ Ol) {
  int b = blockIdx.x;                 // 13200 blocks: 5008 layer + 8192 head
  {
    int x = b & 7, j = b >> 3;        // j in [0,1650)
    b = (j < 626) ? (x * 626 + j) : (5008 + x * 1024 + (j - 626));
  }
  const int lane = threadIdx.x & 63;
  const int wv = threadIdx.x >> 6;
  const int half = lane >> 5;
  const int hl = lane & 31;
  const int v = b * 8 + wv * 2 + half;

  const float4* H4 = (const float4*)Hin;
  const ushort4* Hb4 = (const ushort4*)Hb;

  float dv = dinvg[v];
  int e0 = rowptr[v], e1 = rowptr[v + 1];
  int deg = e1 - e0;

  float4 acc;
  if (v < NLP) {
    acc = H4[(size_t)v * 32 + hl];             // G'[v]
  } else {
    ushort4 t = Hb4[(size_t)(v - HBASE) * 32 + hl];
    acc.x = bfhi_f(t.x);
    acc.y = bfhi_f(t.y);
    acc.z = bfhi_f(t.z);
    acc.w = bfhi_f(t.w);
  }

  int nb = (deg + 15) >> 4;
  int nbo = __shfl_xor(nb, 32);
  int nbmax = max(nb, nbo);

  if (v < NLP) {
    for (int t = 0; t < nbmax; ++t) {
      int e = t * 16;
      unsigned pr = 0;
      if (hl < 16 && e + hl < deg) pr = eg[e0 + e + hl];
      float4 xs[16];
#pragma unroll
      for (int i = 0; i < 16; ++i) {
        unsigned pe = (unsigned)__shfl((int)pr, (half << 5) | i);
        int u = (e + i < deg) ? (int)pe : ZIDX_L;
        xs[i] = H4[(size_t)u * 32 + hl];
      }
#pragma unroll
      for (int i = 0; i < 16; ++i) {
        acc.x += xs[i].x;
        acc.y += xs[i].y;
        acc.z += xs[i].z;
        acc.w += xs[i].w;
      }
    }
  } else {
    for (int t = 0; t < nbmax; ++t) {
      int e = t * 16;
      unsigned pr = 0;
      if (hl < 16 && e + hl < deg) pr = eg[e0 + e + hl];
      ushort4 xs[16];
#pragma unroll
      for (int i = 0; i < 16; ++i) {
        unsigned pe = (unsigned)__shfl((int)pr, (half << 5) | i);
        int u = (e + i < deg) ? (int)pe : ZIDX_H;   // local head ids
        xs[i] = Hb4[(size_t)u * 32 + hl];
      }
#pragma unroll
      for (int i = 0; i < 16; ++i) {
        acc.x += bfhi_f(xs[i].x);
        acc.y += bfhi_f(xs[i].y);
        acc.z += bfhi_f(xs[i].z);
        acc.w += bfhi_f(xs[i].w);
      }
    }
  }

  float4 bb = ((const float4*)bias)[hl];
  acc.x = fmaxf(fmaf(dv, acc.x, bb.x), 0.f);
  acc.y = fmaxf(fmaf(dv, acc.y, bb.y), 0.f);
  acc.z = fmaxf(fmaf(dv, acc.z, bb.z), 0.f);
  acc.w = fmaxf(fmaf(dv, acc.w, bb.w), 0.f);

  if (v < NLP) {
    ushort4 th, tl;
    split2(acc.x, th.x, tl.x);
    split2(acc.y, th.y, tl.y);
    split2(acc.z, th.z, tl.z);
    split2(acc.w, th.w, tl.w);
    ((ushort4*)Oh)[(size_t)v * 32 + hl] = th;
    ((ushort4*)Ol)[(size_t)v * 32 + hl] = tl;
  } else {
    ushort4 th;
    th.x = bf16_rne(acc.x);
    th.y = bf16_rne(acc.y);
    th.z = bf16_rne(acc.z);
    th.w = bf16_rne(acc.w);
    ((ushort4*)Oh)[(size_t)v * 32 + hl] = th;
  }
}

// ---------------- value head ----------------

__global__ __launch_bounds__(128) void value_kernel(const float* __restrict__ hsum,
                                                    const float* __restrict__ w1,
                                                    const float* __restrict__ b1,
                                                    const float* __restrict__ w2,
                                                    const float* __restrict__ b2,
                                                    float* __restrict__ out) {
  __shared__ float hm[128];
  __shared__ float red[128];
  int t = threadIdx.x;
  hm[t] = hsum[t] * (1.0f / (float)N_L);
  __syncthreads();
  float acc = b1[t];
  for (int k = 0; k < 128; ++k) acc = fmaf(hm[k], w1[k * 128 + t], acc);
  red[t] = fmaxf(acc, 0.f) * w2[t];
  for (int off = 64; off > 0; off >>= 1) {
    __syncthreads();
    if (t < off) red[t] += red[t + off];
  }
  __syncthreads();
  if (t == 0) out[0] = red[0] + b2[0];
}

__global__ __launch_bounds__(64) void mask_kernel(const float* __restrict__ lp,
                                                  float* __restrict__ out) {
  int i = threadIdx.x;
  if (i < L_H) out[i] = (lp[i] > 0.5f) ? 1.0f : 0.0f;
}

// ---------------- driver ----------------

extern "C" void kernel_launch(void* const* d_in, const int* in_sizes, int n_in,
                              void* d_out, int out_size, void* d_ws, size_t ws_size,
                              hipStream_t stream) {
  const float* x      = (const float*)d_in[0];
  const int*   ei     = (const int*)d_in[1];
  const float* head_x = (const float*)d_in[2];
  const int*   hei    = (const int*)d_in[3];
  const float* enc_w1 = (const float*)d_in[4];
  const float* enc_b1 = (const float*)d_in[5];
  const float* enc_w2 = (const float*)d_in[6];
  const float* enc_b2 = (const float*)d_in[7];
  const float* gnn_w1 = (const float*)d_in[8];
  const float* gnn_b1 = (const float*)d_in[9];
  const float* gnn_w2 = (const float*)d_in[10];
  const float* gnn_b2 = (const float*)d_in[11];
  const float* lp_w1  = (const float*)d_in[12];
  const float* lp_b1  = (const float*)d_in[13];
  const float* lp_w2  = (const float*)d_in[14];
  const float* lp_b2  = (const float*)d_in[15];
  const float* hp_w1  = (const float*)d_in[16];
  const float* hp_b1  = (const float*)d_in[17];
  const float* hp_w2  = (const float*)d_in[18];
  const float* hp_b2  = (const float*)d_in[19];
  const float* v_w1   = (const float*)d_in[20];
  const float* v_b1   = (const float*)d_in[21];
  const float* v_w2   = (const float*)d_in[22];
  const float* v_b2   = (const float*)d_in[23];
  float* out = (float*)d_out;

  char* base = (char*)d_ws;
  float* SAf = (float*)(base + OFF_SAF);
  unsigned short* Hb = (unsigned short*)(base + OFF_HB);
  unsigned short* SBh = (unsigned short*)(base + OFF_SBH);
  unsigned short* SBl = (unsigned short*)(base + OFF_SBL);
  unsigned short* WTh = (unsigned short*)(base + OFF_WTH);
  unsigned short* WTl = (unsigned short*)(base + OFF_WTL);
  float* dinv_g = (float*)(base + OFF_DINV);
  float* hsum   = (float*)(base + OFF_HSUM);
  int* indeg_g  = (int*)(base + OFF_DEG);
  int* rowptr_g = (int*)(base + OFF_RP);
  unsigned short* eg = (unsigned short*)(base + OFF_EG);
  int* bsum     = (int*)(base + OFF_BSUM);
  int* rank     = (int*)(base + OFF_SBH);   // overlay; consumed by fill blocks

  const int WT_ENC1 = 0, WT_ENC2 = 32768, WT_G1 = 49152, WT_G2 = 65536,
            WT_LP = 81920, WT_HP = 98304;

  const int OUT_LP = 0, OUT_HP = N_L, OUT_MASK = N_L + N_HT, OUT_SV = N_L + N_HT + L_H;

  // ---- CSR + dinv + weight split + zero pad ----
  hipMemsetAsync(indeg_g, 0, (size_t)R_T * sizeof(int), stream);
  hipMemsetAsync(hsum, 0, 128 * sizeof(float), stream);
  hipMemsetAsync(base + OFF_ZPAD, 0, 512, stream);

  prep_csr<<<NB_CONV + NB_FILL, 256, 0, stream>>>(
      enc_w1, enc_w2, gnn_w1, gnn_w2, lp_w1, hp_w1, WTh, WTl,
      ei, hei, indeg_g, rank);

  scan_block<<<(R_T + 1023) / 1024, 1024, 0, stream>>>(indeg_g, R_T, rowptr_g, bsum);
  scan_top128<<<1, 64, 0, stream>>>(bsum, (R_T + 1023) / 1024);
  scan_fix<<<(R_T + 256) / 256, 256, 0, stream>>>(rowptr_g, bsum, indeg_g, dinv_g,
                                                  R_T, (R_T + 1023) / 1024);

  // ---- fused encoder + g1-mm (+ fill backfill blocks) ----
  enc_fused<<<NB_ENC + NB_FILL, 256, 0, stream>>>(
      x, head_x,
      WTh + WT_ENC1, WTl + WT_ENC1,
      WTh + WT_ENC2, WTl + WT_ENC2,
      WTh + WT_G1,   WTl + WT_G1,
      enc_b1, enc_b2, dinv_g, SAf, Hb,
      ei, hei, rowptr_g, rank, eg);

  // ---- GCN layer 1 aggregate ----
  agg_packed<<<R_T / 8, 256, 0, stream>>>(SAf, Hb, dinv_g, rowptr_g, eg, gnn_b1,
                                          SBh, SBl);

  // ---- GCN layer 2 ----
  mm_g<<<R_T / 128, 256, 0, stream>>>(SBh, SBl, WTh + WT_G2, WTl + WT_G2,
                                      dinv_g, SAf, Hb);
  agg_packed<<<R_T / 8, 256, 0, stream>>>(SAf, Hb, dinv_g, rowptr_g, eg, gnn_b2,
                                          SBh, SBl);

  // ---- policy heads (+ colsum backfill) ----
  mm_policy<<<NB_POL + NB_CSUM, 256, 0, stream>>>(
      SBh, SBl,
      WTh + WT_LP, WTl + WT_LP, WTh + WT_HP,
      lp_b1, hp_b1, lp_w2, hp_w2, lp_b2, hp_b2,
      out + OUT_LP, out + OUT_HP, hsum);

  // ---- value ----
  value_kernel<<<1, 128, 0, stream>>>(hsum, v_w1, v_b1, v_w2, v_b2, out + OUT_SV);

  // ---- mask ----
  mask_kernel<<<1, 64, 0, stream>>>(out + OUT_LP, out + OUT_MASK);
}

// Round 20
// 367.622 us; speedup vs baseline: 1.0631x; 1.0137x over previous
//
#include <hip/hip_runtime.h>
#include <math.h>

// PruningAgent r19: r18 +
//  - mm_policy: split-x3 precision ONLY for block 0 (rows 0-127, the mask
//    knife-edge rows); layer blocks 1..312 use single-bf16 (policy mm is a
//    leaf — its rows don't feed back into the mask chain).
//  - colsum backfill reads SBh only (value head has 2e-2 tolerance on a
//    mean of 40000 elements).
//  - value+mask merged into one 2-block dispatch.

typedef unsigned short ushort_t;
using short8 = __attribute__((ext_vector_type(8))) short;
using f32x4  = __attribute__((ext_vector_type(4))) float;

constexpr int N_L  = 40000;
constexpr int E_L  = 640000;
constexpr int L_H  = 8;
constexpr int N_H1 = 8192;
constexpr int E_H1 = 131072;
constexpr int N_HT = 65536;    // 8*8192
constexpr int E_HT = 1048576;  // 8*131072
constexpr int E_T  = E_L + E_HT;
constexpr int NLP  = 40064;    // layer rows padded to 128 (313*128)
constexpr int R_T  = 105600;   // NLP + N_HT
constexpr int HBASE = 40064;

constexpr int NB_ENC  = R_T / 128;            // 825
constexpr int NB_FILL = (E_T + 255) / 256;    // 6592
constexpr int NB_CONV = 448;
constexpr int NB_POL  = R_T / 128;            // 825
constexpr int NB_CSUM = (N_L + 127) / 128;    // 313

// workspace byte offsets
constexpr size_t OFF_SAF  = 0;                            // NLP*512 fp32 G'
constexpr size_t OFF_HB   = (size_t)NLP * 512;            // N_HT*256 bf16 G'
constexpr size_t OFF_ZPAD = OFF_HB + (size_t)N_HT * 256;  // 512 B zeros
constexpr size_t OFF_SBH  = OFF_ZPAD + 512;               // R_T*256 (rank overlay pre-agg)
constexpr size_t OFF_SBL  = OFF_SBH + (size_t)R_T * 256;  // NLP*256
constexpr size_t OFF_WTH  = OFF_SBL + (size_t)NLP * 256;  // 229376
constexpr size_t OFF_WTL  = OFF_WTH + 229376;
constexpr size_t OFF_DINV = OFF_WTL + 229376;             // R_T*4
constexpr size_t OFF_HSUM = OFF_DINV + (size_t)R_T * 4;   // 512
constexpr size_t OFF_DEG  = OFF_HSUM + 512;               // R_T*4 indeg
constexpr size_t OFF_RP   = OFF_DEG + (size_t)R_T * 4;    // (R_T+1)*4 rowptr
constexpr size_t OFF_EG   = OFF_RP + (size_t)(R_T + 1) * 4;  // (E_T+32)*2 u16
constexpr size_t OFF_BSUM = OFF_EG + (size_t)(E_T + 32) * 2; // 512

constexpr int ZIDX_L = (int)(OFF_ZPAD / 512);   // float4-row index of zero row
constexpr int ZIDX_H = N_HT;                    // Hb local row N_HT = ZPAD start

static_assert(OFF_ZPAD % 512 == 0, "zpad alignment");

// ---------------- numeric helpers ----------------

__device__ __forceinline__ unsigned short bf16_rne(float f) {
  unsigned u = __float_as_uint(f);
  unsigned r = u + 0x7FFFu + ((u >> 16) & 1u);
  return (unsigned short)(r >> 16);
}
__device__ __forceinline__ float bfhi_f(unsigned short h) {
  return __uint_as_float((unsigned)h << 16);
}
__device__ __forceinline__ void split2(float f, unsigned short& h, unsigned short& l) {
  h = bf16_rne(f);
  l = bf16_rne(f - bfhi_f(h));
}

__device__ __forceinline__ void gload16(const void* g, void* l) {
  __builtin_amdgcn_global_load_lds((__attribute__((address_space(1))) void*)(g),
                                   (__attribute__((address_space(3))) void*)(l),
                                   16, 0, 0);
}

// ---------------- prep: conv_weights U count_deg ----------------

__global__ __launch_bounds__(256) void prep_csr(
    const float* __restrict__ w0, const float* __restrict__ w1,
    const float* __restrict__ w2, const float* __restrict__ w3,
    const float* __restrict__ w4, const float* __restrict__ w5,
    unsigned short* __restrict__ th, unsigned short* __restrict__ tl,
    const int* __restrict__ ei, const int* __restrict__ hei,
    int* __restrict__ indeg, int* __restrict__ rank) {
  if (blockIdx.x < NB_CONV) {
    int t = blockIdx.x * 256 + threadIdx.x;
    const float* src; int K, dstoff, idx;
    if (t < 32768) { src = w0; K = 256; dstoff = 0; idx = t; }
    else {
      int s = (t - 32768) >> 14;
      idx = (t - 32768) & 16383;
      K = 128;
      dstoff = 32768 + s * 16384;
      src = s == 0 ? w1 : s == 1 ? w2 : s == 2 ? w3 : s == 3 ? w4 : w5;
    }
    int k = idx >> 7, c = idx & 127;
    unsigned short h_, l_;
    split2(src[idx], h_, l_);
    th[dstoff + c * K + k] = h_;
    tl[dstoff + c * K + k] = l_;
  } else {
    int i = (blockIdx.x - NB_CONV) * 256 + threadIdx.x;
    if (i < E_L) {
      rank[i] = atomicAdd(&indeg[ei[E_L + i]], 1);
    } else if (i < E_T) {
      int t = i - E_L;
      int l = t >> 17, e = t & (E_H1 - 1);
      rank[i] = atomicAdd(&indeg[HBASE + l * N_H1 + hei[l * 2 * E_H1 + E_H1 + e]], 1);
    }
  }
}

// ---------------- scans ----------------

__global__ __launch_bounds__(1024) void scan_block(const int* __restrict__ in, int n,
                                                   int* __restrict__ out,
                                                   int* __restrict__ bsum) {
  __shared__ int s[1024];
  int t = threadIdx.x;
  int i = blockIdx.x * 1024 + t;
  int v = (i < n) ? in[i] : 0;
  s[t] = v;
  __syncthreads();
  for (int off = 1; off < 1024; off <<= 1) {
    int x = (t >= off) ? s[t - off] : 0;
    __syncthreads();
    s[t] += x;
    __syncthreads();
  }
  if (i < n) out[i] = s[t] - v;
  if (t == 1023) bsum[blockIdx.x] = s[t];
}

__global__ __launch_bounds__(64) void scan_top128(int* __restrict__ bsum, int nb) {
  int lane = threadIdx.x;
  int a = (lane < nb) ? bsum[lane] : 0;
  int b = (lane + 64 < nb) ? bsum[lane + 64] : 0;
  int ia = a;
  for (int off = 1; off < 64; off <<= 1) {
    int x = __shfl_up(ia, off);
    if (lane >= off) ia += x;
  }
  int ta = __shfl(ia, 63);
  int ib = b;
  for (int off = 1; off < 64; off <<= 1) {
    int x = __shfl_up(ib, off);
    if (lane >= off) ib += x;
  }
  int tb = __shfl(ib, 63);
  if (lane < nb) bsum[lane] = ia - a;
  if (lane + 64 < nb) bsum[lane + 64] = ta + ib - b;
  if (lane == 0) bsum[nb] = ta + tb;
}

// scan_fix + dinv fused
__global__ __launch_bounds__(256) void scan_fix(int* __restrict__ rowptr,
                                                const int* __restrict__ bsum,
                                                const int* __restrict__ indeg,
                                                float* __restrict__ dinv,
                                                int n, int nb) {
  int i = blockIdx.x * 256 + threadIdx.x;
  if (i < n) {
    rowptr[i] += bsum[i >> 10];
    dinv[i] = 1.0f / sqrtf((float)(indeg[i] + 1));
  } else if (i == n) {
    rowptr[n] = bsum[nb];
  }
}

// ---------------- shared mm helpers (KC=64 chunk), SPLIT-templated -------

template <bool SPLIT>
__device__ __forceinline__ void stage_w_t(const unsigned short* Wth,
                                          const unsigned short* Wtl, int K, int kc,
                                          char* Ws_h, char* Ws_l,
                                          int wv, int rsub, int xr) {
#pragma unroll
  for (int j = 0; j < 4; ++j) {
    int q = wv * 4 + j;
    int c = q * 8 + rsub;
    size_t gb = ((size_t)c * K + kc) * 2 + (size_t)xr * 16;
    gload16((const char*)Wth + gb, Ws_h + q * 1024);
    if constexpr (SPLIT) gload16((const char*)Wtl + gb, Ws_l + q * 1024);
  }
}

template <bool SPLIT>
__device__ __forceinline__ void mfma_chunk_t(const char* As_h, const char* As_l,
                                             const char* Ws_h, const char* Ws_l,
                                             int wv, int g, int li,
                                             f32x4 acc[2][8]) {
  short8 fa_h[2][2], fa_l[2][2];
#pragma unroll
  for (int m = 0; m < 2; ++m)
#pragma unroll
    for (int ks = 0; ks < 2; ++ks) {
      int row = wv * 32 + m * 16 + li;
      int off = row * 128 + ks * 64 + g * 16;
      off ^= (row & 7) << 4;
      fa_h[m][ks] = *(const short8*)(As_h + off);
      if constexpr (SPLIT) fa_l[m][ks] = *(const short8*)(As_l + off);
    }
#pragma unroll
  for (int nh = 0; nh < 2; ++nh) {
    short8 fb_h[4][2], fb_l[4][2];
#pragma unroll
    for (int n = 0; n < 4; ++n)
#pragma unroll
      for (int ks = 0; ks < 2; ++ks) {
        int c = nh * 64 + n * 16 + li;
        int off = c * 128 + ks * 64 + g * 16;
        off ^= (c & 7) << 4;
        fb_h[n][ks] = *(const short8*)(Ws_h + off);
        if constexpr (SPLIT) fb_l[n][ks] = *(const short8*)(Ws_l + off);
      }
#pragma unroll
    for (int m = 0; m < 2; ++m)
#pragma unroll
      for (int n = 0; n < 4; ++n)
#pragma unroll
        for (int ks = 0; ks < 2; ++ks) {
          f32x4 a_ = acc[m][nh * 4 + n];
          a_ = __builtin_amdgcn_mfma_f32_16x16x32_bf16(fa_h[m][ks], fb_h[n][ks], a_, 0, 0, 0);
          if constexpr (SPLIT) {
            a_ = __builtin_amdgcn_mfma_f32_16x16x32_bf16(fa_h[m][ks], fb_l[n][ks], a_, 0, 0, 0);
            a_ = __builtin_amdgcn_mfma_f32_16x16x32_bf16(fa_l[m][ks], fb_h[n][ks], a_, 0, 0, 0);
          }
          acc[m][nh * 4 + n] = a_;
        }
  }
}

template <bool SPLIT>
__device__ __forceinline__ void write_h_slice_t(const f32x4 acc[2][8],
                                                const float* bj, int kc,
                                                char* As_h, char* As_l,
                                                int wv, int g, int li) {
#pragma unroll
  for (int m = 0; m < 2; ++m)
#pragma unroll
    for (int jj = 0; jj < 4; ++jj) {
      int j = (kc >> 4) + jj;
#pragma unroll
      for (int r = 0; r < 4; ++r) {
        float o = fmaxf(acc[m][j][r] + bj[j], 0.f);
        int row = wv * 32 + m * 16 + g * 4 + r;
        int cl = jj * 16 + li;
        int byte = row * 128 + ((((cl >> 3) ^ (row & 7)) << 4) | ((cl & 7) * 2));
        if constexpr (SPLIT) {
          unsigned short h_, l_;
          split2(o, h_, l_);
          *(unsigned short*)(As_h + byte) = h_;
          *(unsigned short*)(As_l + byte) = l_;
        } else {
          *(unsigned short*)(As_h + byte) = bf16_rne(o);
        }
      }
    }
}

// G' epilogue: layer rows -> fp32 dinv*h; head rows -> bf16 dinv*h
__device__ __forceinline__ void write_g_out(const f32x4 acc[2][8],
                                            const float* __restrict__ dinvg,
                                            float* __restrict__ G,
                                            unsigned short* __restrict__ Hb,
                                            int row0, int wv, int g, int li) {
  if (row0 < NLP) {
#pragma unroll
    for (int m = 0; m < 2; ++m)
#pragma unroll
      for (int r = 0; r < 4; ++r) {
        int rowg = row0 + wv * 32 + m * 16 + g * 4 + r;
        float dvr = dinvg[rowg];
#pragma unroll
        for (int j = 0; j < 8; ++j)
          G[(size_t)rowg * 128 + j * 16 + li] = acc[m][j][r] * dvr;
      }
  } else {
#pragma unroll
    for (int m = 0; m < 2; ++m)
#pragma unroll
      for (int r = 0; r < 4; ++r) {
        int rowg = row0 + wv * 32 + m * 16 + g * 4 + r;
        float dvr = dinvg[rowg];
        int rl = rowg - HBASE;
#pragma unroll
        for (int j = 0; j < 8; ++j)
          Hb[(size_t)rl * 128 + j * 16 + li] = bf16_rne(acc[m][j][r] * dvr);
      }
  }
}

// ---------------- fused encoder + g1 matmul (+ fill backfill blocks) ------

template <bool SPLIT>
__device__ __forceinline__ void enc_body(
    const float* __restrict__ xs, int lclamp,
    const unsigned short* __restrict__ W1h, const unsigned short* __restrict__ W1l,
    const unsigned short* __restrict__ W2h, const unsigned short* __restrict__ W2l,
    const unsigned short* __restrict__ Wgh, const unsigned short* __restrict__ Wgl,
    const float* __restrict__ b1, const float* __restrict__ b2,
    const float* __restrict__ dinvg,
    float* __restrict__ G, unsigned short* __restrict__ Hb,
    char* As_h, char* As_l, char* Ws_h, char* Ws_l,
    int tid, int wv, int g, int li, int row0, int lrow0, int rsub, int xr) {
  float bj1[8], bj2[8];
#pragma unroll
  for (int j = 0; j < 8; ++j) {
    bj1[j] = b1[j * 16 + li];
    bj2[j] = b2[j * 16 + li];
  }

  f32x4 acc1[2][8];
#pragma unroll
  for (int m = 0; m < 2; ++m)
#pragma unroll
    for (int j = 0; j < 8; ++j) acc1[m][j] = f32x4{0.f, 0.f, 0.f, 0.f};

#pragma unroll
  for (int kc = 0; kc < 256; kc += 64) {
    __syncthreads();
    stage_w_t<SPLIT>(W1h, W1l, 256, kc, Ws_h, Ws_l, wv, rsub, xr);
    {
      int r = tid >> 1, hf = tid & 1;
      int lrow = min(lrow0 + r, lclamp);
      const float* src = xs + (size_t)lrow * 256 + kc + hf * 32;
#pragma unroll
      for (int i = 0; i < 4; ++i) {
        float4 a = ((const float4*)src)[2 * i];
        float4 b = ((const float4*)src)[2 * i + 1];
        float f[8] = {a.x, a.y, a.z, a.w, b.x, b.y, b.z, b.w};
        short8 vh, vl;
#pragma unroll
        for (int e = 0; e < 8; ++e) {
          if constexpr (SPLIT) {
            unsigned short h_, l_;
            split2(f[e], h_, l_);
            vh[e] = (short)h_;
            vl[e] = (short)l_;
          } else {
            vh[e] = (short)bf16_rne(f[e]);
          }
        }
        int xu = hf * 4 + i;
        int u = r * 8 + (xu ^ (r & 7));
        *(short8*)(As_h + u * 16) = vh;
        if constexpr (SPLIT) *(short8*)(As_l + u * 16) = vl;
      }
    }
    __syncthreads();
    mfma_chunk_t<SPLIT>(As_h, As_l, Ws_h, Ws_l, wv, g, li, acc1);
  }

  f32x4 acc2[2][8];
#pragma unroll
  for (int m = 0; m < 2; ++m)
#pragma unroll
    for (int j = 0; j < 8; ++j) acc2[m][j] = f32x4{0.f, 0.f, 0.f, 0.f};

#pragma unroll
  for (int kc = 0; kc < 128; kc += 64) {
    __syncthreads();
    stage_w_t<SPLIT>(W2h, W2l, 128, kc, Ws_h, Ws_l, wv, rsub, xr);
    write_h_slice_t<SPLIT>(acc1, bj1, kc, As_h, As_l, wv, g, li);
    __syncthreads();
    mfma_chunk_t<SPLIT>(As_h, As_l, Ws_h, Ws_l, wv, g, li, acc2);
  }

  f32x4 acc3[2][8];
#pragma unroll
  for (int m = 0; m < 2; ++m)
#pragma unroll
    for (int j = 0; j < 8; ++j) acc3[m][j] = f32x4{0.f, 0.f, 0.f, 0.f};

#pragma unroll
  for (int kc = 0; kc < 128; kc += 64) {
    __syncthreads();
    stage_w_t<SPLIT>(Wgh, Wgl, 128, kc, Ws_h, Ws_l, wv, rsub, xr);
    write_h_slice_t<SPLIT>(acc2, bj2, kc, As_h, As_l, wv, g, li);
    __syncthreads();
    mfma_chunk_t<SPLIT>(As_h, As_l, Ws_h, Ws_l, wv, g, li, acc3);
  }

  write_g_out(acc3, dinvg, G, Hb, row0, wv, g, li);
}

__global__ __launch_bounds__(256, 2) void enc_fused(
    const float* __restrict__ x, const float* __restrict__ head_x,
    const unsigned short* __restrict__ W1h, const unsigned short* __restrict__ W1l,
    const unsigned short* __restrict__ W2h, const unsigned short* __restrict__ W2l,
    const unsigned short* __restrict__ Wgh, const unsigned short* __restrict__ Wgl,
    const float* __restrict__ b1, const float* __restrict__ b2,
    const float* __restrict__ dinvg,
    float* __restrict__ G, unsigned short* __restrict__ Hb,
    const int* __restrict__ ei, const int* __restrict__ hei,
    const int* __restrict__ rowptr, const int* __restrict__ rank,
    unsigned short* __restrict__ eg) {
  __shared__ __align__(16) char lds[65536];

  if (blockIdx.x >= NB_ENC) {
    // ---- fill backfill blocks (u16 local ids) ----
    int i = (blockIdx.x - NB_ENC) * 256 + threadIdx.x;
    if (i < E_L) {
      int dst = ei[E_L + i];
      int src = ei[i];                       // local == global for layer
      eg[rowptr[dst] + rank[i]] = (unsigned short)src;
    } else if (i < E_T) {
      int t = i - E_L;
      int l = t >> 17, e = t & (E_H1 - 1);
      int b2o = l * 2 * E_H1;
      int dst = HBASE + l * N_H1 + hei[b2o + E_H1 + e];
      int srcl = l * N_H1 + hei[b2o + e];    // head-local id
      eg[rowptr[dst] + rank[i]] = (unsigned short)srcl;
    }
    return;
  }

  char* As_h = lds;
  char* As_l = lds + 16384;
  char* Ws_h = lds + 32768;
  char* Ws_l = lds + 49152;

  const int tid = threadIdx.x;
  const int lane = tid & 63;
  const int wv = tid >> 6;
  const int g = lane >> 4;
  const int li = lane & 15;
  const int row0 = blockIdx.x * 128;
  const int rsub = lane >> 3;
  const int xr = (lane & 7) ^ ((lane >> 3) & 7);

  if (row0 < NLP) {
    enc_body<true>(x, N_L - 1, W1h, W1l, W2h, W2l, Wgh, Wgl, b1, b2, dinvg, G, Hb,
                   As_h, As_l, Ws_h, Ws_l, tid, wv, g, li, row0, row0, rsub, xr);
  } else {
    enc_body<false>(head_x, N_HT - 1, W1h, nullptr, W2h, nullptr, Wgh, nullptr,
                    b1, b2, dinvg, G, Hb,
                    As_h, As_l, Ws_h, Ws_l, tid, wv, g, li, row0, row0 - NLP,
                    rsub, xr);
  }
}

// ---------------- MFMA matmul (g2: split/single in, scaled hybrid out) -----

template <bool SPLIT>
__device__ __forceinline__ void mm_g_body(
    const unsigned short* __restrict__ Ah, const unsigned short* __restrict__ Al,
    const unsigned short* __restrict__ Wth, const unsigned short* __restrict__ Wtl,
    char* As_h, char* As_l, char* Ws_h, char* Ws_l,
    int wv, int g, int li, int row0, int rsub, int xr, f32x4 acc[2][8]) {
  constexpr int K = 128;
#pragma unroll
  for (int kc = 0; kc < K; kc += 64) {
    __syncthreads();
    stage_w_t<SPLIT>(Wth, Wtl, K, kc, Ws_h, Ws_l, wv, rsub, xr);
#pragma unroll
    for (int j = 0; j < 4; ++j) {
      int q = wv * 4 + j;
      int r = q * 8 + rsub;
      size_t gb = ((size_t)(row0 + r) * K + kc) * 2 + (size_t)xr * 16;
      gload16((const char*)Ah + gb, As_h + q * 1024);
      if constexpr (SPLIT) gload16((const char*)Al + gb, As_l + q * 1024);
    }
    __syncthreads();
    mfma_chunk_t<SPLIT>(As_h, As_l, Ws_h, Ws_l, wv, g, li, acc);
  }
}

__global__ __launch_bounds__(256) void mm_g(
    const unsigned short* __restrict__ Ah, const unsigned short* __restrict__ Al,
    const unsigned short* __restrict__ Wth, const unsigned short* __restrict__ Wtl,
    const float* __restrict__ dinvg,
    float* __restrict__ Cf, unsigned short* __restrict__ Hb) {
  __shared__ __align__(16) char lds[65536];
  char* As_h = lds;
  char* As_l = lds + 16384;
  char* Ws_h = lds + 32768;
  char* Ws_l = lds + 49152;

  const int tid = threadIdx.x;
  const int lane = tid & 63;
  const int wv = tid >> 6;
  const int g = lane >> 4;
  const int li = lane & 15;
  const int row0 = blockIdx.x * 128;
  const int rsub = lane >> 3;
  const int xr = (lane & 7) ^ ((lane >> 3) & 7);

  f32x4 acc[2][8];
#pragma unroll
  for (int m = 0; m < 2; ++m)
#pragma unroll
    for (int j = 0; j < 8; ++j) acc[m][j] = f32x4{0.f, 0.f, 0.f, 0.f};

  if (row0 < NLP)
    mm_g_body<true>(Ah, Al, Wth, Wtl, As_h, As_l, Ws_h, Ws_l,
                    wv, g, li, row0, rsub, xr, acc);
  else
    mm_g_body<false>(Ah, nullptr, Wth, nullptr, As_h, As_l, Ws_h, Ws_l,
                     wv, g, li, row0, rsub, xr, acc);

  write_g_out(acc, dinvg, Cf, Hb, row0, wv, g, li);
}

// ---------------- fused policy matmul (+ colsum backfill blocks) ----------
// Precision: split-x3 ONLY block 0 (mask rows 0..7 live in rows 0..127);
// all other blocks single-bf16 (policy outputs are leaves, 2e-2 tol).

__global__ __launch_bounds__(256) void mm_policy(
    const unsigned short* __restrict__ Ah, const unsigned short* __restrict__ Al,
    const unsigned short* __restrict__ Wth_l, const unsigned short* __restrict__ Wtl_l,
    const unsigned short* __restrict__ Wth_h,
    const float* __restrict__ b1l, const float* __restrict__ b1h,
    const float* __restrict__ w2l, const float* __restrict__ w2h,
    const float* __restrict__ b2l, const float* __restrict__ b2h,
    float* __restrict__ out_l, float* __restrict__ out_h,
    float* __restrict__ hsum) {
  __shared__ __align__(16) char lds[65536];

  if (blockIdx.x >= NB_POL) {
    // ---- colsum backfill: partial column sums of SBh (layer rows) ----
    int cb = blockIdx.x - NB_POL;
    int f = threadIdx.x & 127;
    int half = threadIdx.x >> 7;
    int r0 = cb * 128 + half * 64;
    int r1 = min(r0 + 64, N_L);
    float acc = 0.f;
    for (int r = r0; r < r1; ++r)
      acc += bfhi_f(Ah[(size_t)r * 128 + f]);
    atomicAdd(&hsum[f], acc);
    return;
  }

  char* As_h = lds;
  char* As_l = lds + 16384;
  char* Ws_h = lds + 32768;
  char* Ws_l = lds + 49152;

  const int tid = threadIdx.x;
  const int lane = tid & 63;
  const int wv = tid >> 6;
  const int g = lane >> 4;
  const int li = lane & 15;
  const int row0 = blockIdx.x * 128;
  const bool isl = row0 < NLP;
  const int rsub = lane >> 3;
  const int xr = (lane & 7) ^ ((lane >> 3) & 7);

  const float* bias = isl ? b1l : b1h;
  const float* pw2  = isl ? w2l : w2h;
  const float* pb2  = isl ? b2l : b2h;

  f32x4 acc[2][8];
#pragma unroll
  for (int m = 0; m < 2; ++m)
#pragma unroll
    for (int j = 0; j < 8; ++j) acc[m][j] = f32x4{0.f, 0.f, 0.f, 0.f};

  if (row0 == 0)        // mask knife-edge rows: exact split-x3
    mm_g_body<true>(Ah, Al, Wth_l, Wtl_l, As_h, As_l, Ws_h, Ws_l,
                    wv, g, li, row0, rsub, xr, acc);
  else if (isl)         // other layer rows: single-bf16 (leaf, 2e-2 tol)
    mm_g_body<false>(Ah, nullptr, Wth_l, nullptr, As_h, As_l, Ws_h, Ws_l,
                     wv, g, li, row0, rsub, xr, acc);
  else
    mm_g_body<false>(Ah, nullptr, Wth_h, nullptr, As_h, As_l, Ws_h, Ws_l,
                     wv, g, li, row0, rsub, xr, acc);

  float w2c[8], bj[8];
#pragma unroll
  for (int j = 0; j < 8; ++j) {
    w2c[j] = pw2[j * 16 + li];
    bj[j]  = bias[j * 16 + li];
  }
#pragma unroll
  for (int m = 0; m < 2; ++m)
#pragma unroll
    for (int r = 0; r < 4; ++r) {
      float p = 0.f;
#pragma unroll
      for (int j = 0; j < 8; ++j) {
        float o = fmaxf(acc[m][j][r] + bj[j], 0.f);
        p = fmaf(o, w2c[j], p);
      }
      p += __shfl_xor(p, 1);
      p += __shfl_xor(p, 2);
      p += __shfl_xor(p, 4);
      p += __shfl_xor(p, 8);
      if (li == 0) {
        int rowg = row0 + wv * 32 + m * 16 + g * 4 + r;
        if (isl) {
          if (rowg < N_L) out_l[rowg] = 1.0f / (1.0f + expf(-(p + pb2[0])));
        } else {
          out_h[rowg - HBASE] = 1.0f / (1.0f + expf(-(p + pb2[0])));
        }
      }
    }
}

// ---------------- GCN aggregation (pure-add gather, rowptr CSR, u16 eg) ----

__global__ __launch_bounds__(256) void agg_packed(const float* __restrict__ Hin,
                                                  const unsigned short* __restrict__ Hb,
                                                  const float* __restrict__ dinvg,
                                                  const int* __restrict__ rowptr,
                                                  const unsigned short* __restrict__ eg,
                                                  const float* __restrict__ bias,
                                                  unsigned short* __restrict__ Oh,
                                                  unsigned short* __restrict__ Ol) {
  int b = blockIdx.x;                 // 13200 blocks: 5008 layer + 8192 head
  {
    int x = b & 7, j = b >> 3;        // j in [0,1650)
    b = (j < 626) ? (x * 626 + j) : (5008 + x * 1024 + (j - 626));
  }
  const int lane = threadIdx.x & 63;
  const int wv = threadIdx.x >> 6;
  const int half = lane >> 5;
  const int hl = lane & 31;
  const int v = b * 8 + wv * 2 + half;

  const float4* H4 = (const float4*)Hin;
  const ushort4* Hb4 = (const ushort4*)Hb;

  float dv = dinvg[v];
  int e0 = rowptr[v], e1 = rowptr[v + 1];
  int deg = e1 - e0;

  float4 acc;
  if (v < NLP) {
    acc = H4[(size_t)v * 32 + hl];             // G'[v]
  } else {
    ushort4 t = Hb4[(size_t)(v - HBASE) * 32 + hl];
    acc.x = bfhi_f(t.x);
    acc.y = bfhi_f(t.y);
    acc.z = bfhi_f(t.z);
    acc.w = bfhi_f(t.w);
  }

  int nb = (deg + 15) >> 4;
  int nbo = __shfl_xor(nb, 32);
  int nbmax = max(nb, nbo);

  if (v < NLP) {
    for (int t = 0; t < nbmax; ++t) {
      int e = t * 16;
      unsigned pr = 0;
      if (hl < 16 && e + hl < deg) pr = eg[e0 + e + hl];
      float4 xs[16];
#pragma unroll
      for (int i = 0; i < 16; ++i) {
        unsigned pe = (unsigned)__shfl((int)pr, (half << 5) | i);
        int u = (e + i < deg) ? (int)pe : ZIDX_L;
        xs[i] = H4[(size_t)u * 32 + hl];
      }
#pragma unroll
      for (int i = 0; i < 16; ++i) {
        acc.x += xs[i].x;
        acc.y += xs[i].y;
        acc.z += xs[i].z;
        acc.w += xs[i].w;
      }
    }
  } else {
    for (int t = 0; t < nbmax; ++t) {
      int e = t * 16;
      unsigned pr = 0;
      if (hl < 16 && e + hl < deg) pr = eg[e0 + e + hl];
      ushort4 xs[16];
#pragma unroll
      for (int i = 0; i < 16; ++i) {
        unsigned pe = (unsigned)__shfl((int)pr, (half << 5) | i);
        int u = (e + i < deg) ? (int)pe : ZIDX_H;   // local head ids
        xs[i] = Hb4[(size_t)u * 32 + hl];
      }
#pragma unroll
      for (int i = 0; i < 16; ++i) {
        acc.x += bfhi_f(xs[i].x);
        acc.y += bfhi_f(xs[i].y);
        acc.z += bfhi_f(xs[i].z);
        acc.w += bfhi_f(xs[i].w);
      }
    }
  }

  float4 bb = ((const float4*)bias)[hl];
  acc.x = fmaxf(fmaf(dv, acc.x, bb.x), 0.f);
  acc.y = fmaxf(fmaf(dv, acc.y, bb.y), 0.f);
  acc.z = fmaxf(fmaf(dv, acc.z, bb.z), 0.f);
  acc.w = fmaxf(fmaf(dv, acc.w, bb.w), 0.f);

  if (v < NLP) {
    ushort4 th, tl;
    split2(acc.x, th.x, tl.x);
    split2(acc.y, th.y, tl.y);
    split2(acc.z, th.z, tl.z);
    split2(acc.w, th.w, tl.w);
    ((ushort4*)Oh)[(size_t)v * 32 + hl] = th;
    ((ushort4*)Ol)[(size_t)v * 32 + hl] = tl;
  } else {
    ushort4 th;
    th.x = bf16_rne(acc.x);
    th.y = bf16_rne(acc.y);
    th.z = bf16_rne(acc.z);
    th.w = bf16_rne(acc.w);
    ((ushort4*)Oh)[(size_t)v * 32 + hl] = th;
  }
}

// ---------------- value + mask (merged) ----------------

__global__ __launch_bounds__(128) void value_mask_kernel(
    const float* __restrict__ hsum,
    const float* __restrict__ w1, const float* __restrict__ b1,
    const float* __restrict__ w2, const float* __restrict__ b2,
    const float* __restrict__ lp,
    float* __restrict__ out_sv, float* __restrict__ out_mask) {
  if (blockIdx.x == 1) {
    int i = threadIdx.x;
    if (i < L_H) out_mask[i] = (lp[i] > 0.5f) ? 1.0f : 0.0f;
    return;
  }
  __shared__ float hm[128];
  __shared__ float red[128];
  int t = threadIdx.x;
  hm[t] = hsum[t] * (1.0f / (float)N_L);
  __syncthreads();
  float acc = b1[t];
  for (int k = 0; k < 128; ++k) acc = fmaf(hm[k], w1[k * 128 + t], acc);
  red[t] = fmaxf(acc, 0.f) * w2[t];
  for (int off = 64; off > 0; off >>= 1) {
    __syncthreads();
    if (t < off) red[t] += red[t + off];
  }
  __syncthreads();
  if (t == 0) out_sv[0] = red[0] + b2[0];
}

// ---------------- driver ----------------

extern "C" void kernel_launch(void* const* d_in, const int* in_sizes, int n_in,
                              void* d_out, int out_size, void* d_ws, size_t ws_size,
                              hipStream_t stream) {
  const float* x      = (const float*)d_in[0];
  const int*   ei     = (const int*)d_in[1];
  const float* head_x = (const float*)d_in[2];
  const int*   hei    = (const int*)d_in[3];
  const float* enc_w1 = (const float*)d_in[4];
  const float* enc_b1 = (const float*)d_in[5];
  const float* enc_w2 = (const float*)d_in[6];
  const float* enc_b2 = (const float*)d_in[7];
  const float* gnn_w1 = (const float*)d_in[8];
  const float* gnn_b1 = (const float*)d_in[9];
  const float* gnn_w2 = (const float*)d_in[10];
  const float* gnn_b2 = (const float*)d_in[11];
  const float* lp_w1  = (const float*)d_in[12];
  const float* lp_b1  = (const float*)d_in[13];
  const float* lp_w2  = (const float*)d_in[14];
  const float* lp_b2  = (const float*)d_in[15];
  const float* hp_w1  = (const float*)d_in[16];
  const float* hp_b1  = (const float*)d_in[17];
  const float* hp_w2  = (const float*)d_in[18];
  const float* hp_b2  = (const float*)d_in[19];
  const float* v_w1   = (const float*)d_in[20];
  const float* v_b1   = (const float*)d_in[21];
  const float* v_w2   = (const float*)d_in[22];
  const float* v_b2   = (const float*)d_in[23];
  float* out = (float*)d_out;

  char* base = (char*)d_ws;
  float* SAf = (float*)(base + OFF_SAF);
  unsigned short* Hb = (unsigned short*)(base + OFF_HB);
  unsigned short* SBh = (unsigned short*)(base + OFF_SBH);
  unsigned short* SBl = (unsigned short*)(base + OFF_SBL);
  unsigned short* WTh = (unsigned short*)(base + OFF_WTH);
  unsigned short* WTl = (unsigned short*)(base + OFF_WTL);
  float* dinv_g = (float*)(base + OFF_DINV);
  float* hsum   = (float*)(base + OFF_HSUM);
  int* indeg_g  = (int*)(base + OFF_DEG);
  int* rowptr_g = (int*)(base + OFF_RP);
  unsigned short* eg = (unsigned short*)(base + OFF_EG);
  int* bsum     = (int*)(base + OFF_BSUM);
  int* rank     = (int*)(base + OFF_SBH);   // overlay; consumed by fill blocks

  const int WT_ENC1 = 0, WT_ENC2 = 32768, WT_G1 = 49152, WT_G2 = 65536,
            WT_LP = 81920, WT_HP = 98304;

  const int OUT_LP = 0, OUT_HP = N_L, OUT_MASK = N_L + N_HT, OUT_SV = N_L + N_HT + L_H;

  // ---- CSR + dinv + weight split + zero pad ----
  hipMemsetAsync(indeg_g, 0, (size_t)R_T * sizeof(int), stream);
  hipMemsetAsync(hsum, 0, 128 * sizeof(float), stream);
  hipMemsetAsync(base + OFF_ZPAD, 0, 512, stream);

  prep_csr<<<NB_CONV + NB_FILL, 256, 0, stream>>>(
      enc_w1, enc_w2, gnn_w1, gnn_w2, lp_w1, hp_w1, WTh, WTl,
      ei, hei, indeg_g, rank);

  scan_block<<<(R_T + 1023) / 1024, 1024, 0, stream>>>(indeg_g, R_T, rowptr_g, bsum);
  scan_top128<<<1, 64, 0, stream>>>(bsum, (R_T + 1023) / 1024);
  scan_fix<<<(R_T + 256) / 256, 256, 0, stream>>>(rowptr_g, bsum, indeg_g, dinv_g,
                                                  R_T, (R_T + 1023) / 1024);

  // ---- fused encoder + g1-mm (+ fill backfill blocks) ----
  enc_fused<<<NB_ENC + NB_FILL, 256, 0, stream>>>(
      x, head_x,
      WTh + WT_ENC1, WTl + WT_ENC1,
      WTh + WT_ENC2, WTl + WT_ENC2,
      WTh + WT_G1,   WTl + WT_G1,
      enc_b1, enc_b2, dinv_g, SAf, Hb,
      ei, hei, rowptr_g, rank, eg);

  // ---- GCN layer 1 aggregate ----
  agg_packed<<<R_T / 8, 256, 0, stream>>>(SAf, Hb, dinv_g, rowptr_g, eg, gnn_b1,
                                          SBh, SBl);

  // ---- GCN layer 2 ----
  mm_g<<<R_T / 128, 256, 0, stream>>>(SBh, SBl, WTh + WT_G2, WTl + WT_G2,
                                      dinv_g, SAf, Hb);
  agg_packed<<<R_T / 8, 256, 0, stream>>>(SAf, Hb, dinv_g, rowptr_g, eg, gnn_b2,
                                          SBh, SBl);

  // ---- policy heads (+ colsum backfill) ----
  mm_policy<<<NB_POL + NB_CSUM, 256, 0, stream>>>(
      SBh, SBl,
      WTh + WT_LP, WTl + WT_LP, WTh + WT_HP,
      lp_b1, hp_b1, lp_w2, hp_w2, lp_b2, hp_b2,
      out + OUT_LP, out + OUT_HP, hsum);

  // ---- value + mask ----
  value_mask_kernel<<<2, 128, 0, stream>>>(hsum, v_w1, v_b1, v_w2, v_b2,
                                           out + OUT_LP, out + OUT_SV,
                                           out + OUT_MASK);
}